// Round 1
// baseline (30922.314 us; speedup 1.0000x reference)
//
#include <hip/hip_runtime.h>

typedef unsigned short u16;
typedef unsigned int u32;
typedef __attribute__((ext_vector_type(4))) float f32x4;
typedef __attribute__((ext_vector_type(8))) short short8;
typedef __attribute__((ext_vector_type(4))) short short4v;

__device__ __forceinline__ float bf2f(u16 v){ u32 b = ((u32)v)<<16; float f; __builtin_memcpy(&f,&b,4); return f; }
__device__ __forceinline__ u16 f2bf(float f){ u32 b; __builtin_memcpy(&b,&f,4); b = b + 0x7fffu + ((b>>16)&1u); return (u16)(b>>16); }
__device__ __forceinline__ float sigm(float x){ return 1.f/(1.f+__expf(-x)); }
__device__ __forceinline__ float tanh_a(float x){ return 1.f - 2.f/(__expf(2.f*x)+1.f); }

typedef const __attribute__((address_space(1))) u32* gas1;
typedef __attribute__((address_space(3))) u32* las3;
__device__ __forceinline__ void gld16(const u16* g, u16* l){
  __builtin_amdgcn_global_load_lds((gas1)g, (las3)l, 16, 0, 0);
}

// ---------------- pack / cast kernels ----------------
__global__ void cast_x_kernel(const float* __restrict__ in, u16* __restrict__ out){
  int i = blockIdx.x*256 + threadIdx.x;
  for (; i < 4194304; i += 2048*256){
    f32x4 v = ((const f32x4*)in)[i];
    short4v o;
    o[0]=(short)f2bf(v[0]); o[1]=(short)f2bf(v[1]); o[2]=(short)f2bf(v[2]); o[3]=(short)f2bf(v[3]);
    ((short4v*)out)[i] = o;
  }
}

// w[4,512,512] (g,i,h) -> wt[n=g*512+h][k=i]  for w1, wx[l], wh[l]
__global__ void pack_w_kernel(const float* __restrict__ w1, const float* __restrict__ wx, const float* __restrict__ wh,
                              u16* __restrict__ w1p, u16* __restrict__ wxp, u16* __restrict__ whp){
  int e = blockIdx.x*256 + threadIdx.x;
  for (; e < 7340032; e += 2048*256){
    int m = e >> 20; int r = e & 1048575;
    int h = r & 511, k = (r>>9)&511, g = r>>18;
    const float* src; u16* dst;
    if (m==0){ src=w1; dst=w1p; }
    else if (m<=3){ src = wx + (size_t)(m-1)*1048576; dst = wxp + (size_t)(m-1)*1048576; }
    else { src = wh + (size_t)(m-4)*1048576; dst = whp + (size_t)(m-4)*1048576; }
    dst[(size_t)(g*512 + h)*512 + k] = f2bf(src[(size_t)g*262144 + (size_t)k*512 + h]);
  }
}

// u1[4,512,512] cast straight; uv[l][0] -> uv0p[l][512][512]
__global__ void cast_u_kernel(const float* __restrict__ u1, const float* __restrict__ uv,
                              u16* __restrict__ u1p, u16* __restrict__ uv0p){
  int e = blockIdx.x*256 + threadIdx.x;
  for (; e < 1835008; e += 1024*256){
    if (e < 1048576) u1p[e] = f2bf(u1[e]);
    else { int r = e - 1048576; int l = r >> 18; int q = r & 262143; uv0p[r] = f2bf(uv[(size_t)l*1048576 + q]); }
  }
}

// ---------------- GEMM: pre[bt,n] = sum_p A_p @ B_p^T + bias ----------------
// A [32768,512] bf16 row-major; B [2048,512] bf16 row-major (N,K); out bf16 [32768,2048]
__global__ __launch_bounds__(256) void gemm_pre_kernel(
    const u16* __restrict__ A1, const u16* __restrict__ B1,
    const u16* __restrict__ A2, const u16* __restrict__ B2,
    const float* __restrict__ bias, int bmask,
    u16* __restrict__ Out, int nPass)
{
  __shared__ u16 As[128*64];
  __shared__ u16 Bs[128*64];
  const int tid = threadIdx.x;
  const int w = tid>>6, lane = tid&63;
  const int l15 = lane&15, l4 = lane>>4;
  const int m0 = blockIdx.x*128, n0 = blockIdx.y*128;
  const int wm = w>>1, wn = w&1;
  f32x4 acc[4][4];
#pragma unroll
  for (int a=0;a<4;a++)
#pragma unroll
    for (int bq=0;bq<4;bq++) acc[a][bq] = (f32x4){0.f,0.f,0.f,0.f};

  for (int p=0;p<nPass;p++){
    const u16* Ap = p ? A2 : A1;
    const u16* Bp = p ? B2 : B1;
    for (int kt=0;kt<8;kt++){
      const int k0 = kt*64;
      __syncthreads();
#pragma unroll
      for (int i=0;i<4;i++){
        int chunk = w*4 + i;             // 16 chunks of 1KB each
        int fb = chunk*1024 + lane*16;   // byte in 16KB tile
        int row = fb>>7;                 // 128B per row (64 bf16)
        int slot = (fb>>4)&7;
        // linear LDS dest + inverse-swizzled source (so reads can XOR-swizzle)
        const u16* srcA = Ap + (size_t)(m0+row)*512 + k0 + ((slot ^ (row&7))<<3);
        gld16(srcA, (u16*)As + chunk*512);
        const u16* srcB = Bp + (size_t)(n0+row)*512 + k0 + ((slot ^ (row&7))<<3);
        gld16(srcB, (u16*)Bs + chunk*512);
      }
      __syncthreads();
#pragma unroll
      for (int kk=0;kk<2;kk++){
        short8 af[4], bfq[4];
#pragma unroll
        for (int mi=0;mi<4;mi++){
          int row = wm*64 + mi*16 + l15;
          int s16 = l4 + kk*4;
          af[mi] = *(const short8*)&As[row*64 + ((s16 ^ (row&7))<<3)];
        }
#pragma unroll
        for (int ni=0;ni<4;ni++){
          int row = wn*64 + ni*16 + l15;
          int s16 = l4 + kk*4;
          bfq[ni] = *(const short8*)&Bs[row*64 + ((s16 ^ (row&7))<<3)];
        }
#pragma unroll
        for (int mi=0;mi<4;mi++)
#pragma unroll
          for (int ni=0;ni<4;ni++)
            acc[mi][ni] = __builtin_amdgcn_mfma_f32_16x16x32_bf16(af[mi], bfq[ni], acc[mi][ni], 0,0,0);
      }
    }
  }
#pragma unroll
  for (int ni=0;ni<4;ni++){
    int col = n0 + wn*64 + ni*16 + l15;
    float bb = bias[col & bmask];
#pragma unroll
    for (int mi=0;mi<4;mi++){
#pragma unroll
      for (int i=0;i<4;i++){
        int row = m0 + wm*64 + mi*16 + l4*4 + i;
        Out[(size_t)row*2048 + col] = f2bf(acc[mi][ni][i] + bb);
      }
    }
  }
}

// ---------------- scan layer 1 (4 distinct U gates) ----------------
// grid 32: gk=wg&15 owns 32 h-cols (128 U-cols incl 4 gates); gb=wg>>4 owns 16 batches
__global__ __launch_bounds__(512) void scan1_kernel(
    const u16* __restrict__ pre, const u16* __restrict__ u1p,
    u16* __restrict__ hv_out, u32* h_tag)
{
  __shared__ u16 hs[16*512];
  __shared__ float recb[16*128];
  const int tid = threadIdx.x;
  const int wg = blockIdx.x;
  const int gk = wg & 15, gb = wg >> 4;
  const int b0 = gb*16, kb = gk*32;
  const int w = tid>>6, lane = tid&63;
  const int l15 = lane&15, l4 = lane>>4;
  const int g = w>>1;
  const int colw = (w&1)*16;

  short8 bf[16];   // U1 slice resident in registers: B[k][col], col = kb+colw+l15 of gate g
  {
    const u16* up = u1p + (size_t)g*262144 + (kb + colw + l15);
#pragma unroll
    for (int s=0;s<16;s++){
      int kbase = s*32 + l4*8;
#pragma unroll
      for (int j=0;j<8;j++) bf[s][j] = (short)up[(size_t)(kbase+j)*512];
    }
  }
  {
    short8 z = {0,0,0,0,0,0,0,0};
    for (int i = tid; i < 1024; i += 512) ((short8*)hs)[i] = z;
  }
  const int b = tid>>5, kl = tid&31;
  float c = 0.f;
  __syncthreads();

  for (int t=0; t<1024; ++t){
    // early pre loads (overlap with MFMA)
    const u16* prow = pre + ((size_t)((b0+b)*1024 + t))*2048 + kb + kl;
    float p0 = bf2f(prow[0]), p1 = bf2f(prow[512]), p2 = bf2f(prow[1024]), p3 = bf2f(prow[1536]);
    // rec = h @ U  (A: row=b=l15, k packed; B in regs)
    f32x4 acc = {0.f,0.f,0.f,0.f};
    {
      int rb = l15*512;
#pragma unroll
      for (int s=0;s<16;s++){
        int ku = s*32 + l4*8;
        short8 a = *(const short8*)&hs[rb + (ku ^ ((l15&7)<<3))];
        acc = __builtin_amdgcn_mfma_f32_16x16x32_bf16(a, bf[s], acc, 0,0,0);
      }
    }
    {
      int rr = l4*4, rc = w*16 + l15;
#pragma unroll
      for (int i=0;i<4;i++) recb[(rr+i)*128 + rc] = acc[i];
    }
    __syncthreads();
    // gates: thread owns (b, kl)
    float ri = recb[b*128 + kl],     rf = recb[b*128 + 32 + kl];
    float rg = recb[b*128 + 64 + kl], ro = recb[b*128 + 96 + kl];
    float gi = sigm(p0+ri), gf = sigm(p1+rf), gg = sigm(p2+rg), go = sigm(p3+ro);
    c = gf + c + gi*gg;
    float h = go + tanh_a(c);
    u16 hb = f2bf(h);
    hv_out[((size_t)((b0+b)*1024 + t))*512 + kb + kl] = hb;
    u32 tag = (u32)(t+1) & 0xffffu;
    __hip_atomic_store(&h_tag[(size_t)((t&1)*32 + b0 + b)*512 + kb + kl], (tag<<16)|(u32)hb,
                       __ATOMIC_RELAXED, __HIP_MEMORY_SCOPE_AGENT);
    // gather full h for this b-group (tag-validated, self-ordering)
    {
      const u32* src = &h_tag[(size_t)((t&1)*32 + b0)*512];
      u32 v[16];
#pragma unroll
      for (int j=0;j<16;j++) v[j] = __hip_atomic_load(&src[b*512 + kl + 32*j], __ATOMIC_RELAXED, __HIP_MEMORY_SCOPE_AGENT);
      u32 done = 0;
      while (done != 0xffffu){
#pragma unroll
        for (int j=0;j<16;j++){
          if (!((done>>j)&1)){
            if ((v[j]>>16) == tag) done |= 1u<<j;
            else v[j] = __hip_atomic_load(&src[b*512 + kl + 32*j], __ATOMIC_RELAXED, __HIP_MEMORY_SCOPE_AGENT);
          }
        }
      }
#pragma unroll
      for (int j=0;j<16;j++){
        int k = kl + 32*j;
        hs[b*512 + (k ^ ((b&7)<<3))] = (u16)(v[j] & 0xffffu);
      }
    }
    __syncthreads();
  }
}

// ---------------- scan layers 2..4 (shared u[0], shared rec across gates) ----------------
// grid 16: gk=wg&7 owns 64 h-cols; gb=wg>>3 owns 16 batches
__global__ __launch_bounds__(256) void scan2_kernel(
    const u16* __restrict__ pre, const u16* __restrict__ u0p,
    u16* __restrict__ hv_out, u32* h_tag, int epoch, int is_last, float* __restrict__ out)
{
  __shared__ u16 hs[16*512];
  __shared__ float recb[16*64];
  const int tid = threadIdx.x;
  const int wg = blockIdx.x;
  const int gk = wg & 7, gb = wg >> 3;
  const int b0 = gb*16, kb = gk*64;
  const int w = tid>>6, lane = tid&63;
  const int l15 = lane&15, l4 = lane>>4;

  short8 bf[16];
  {
    const u16* up = u0p + (kb + w*16 + l15);
#pragma unroll
    for (int s=0;s<16;s++){
      int kbase = s*32 + l4*8;
#pragma unroll
      for (int j=0;j<8;j++) bf[s][j] = (short)up[(size_t)(kbase+j)*512];
    }
  }
  {
    short8 z = {0,0,0,0,0,0,0,0};
    for (int i = tid; i < 1024; i += 256) ((short8*)hs)[i] = z;
  }
  const int b = tid>>4, kl0 = (tid&15)*4;
  f32x4 cv = {0.f,0.f,0.f,0.f};
  __syncthreads();

  for (int t=0; t<1024; ++t){
    const u16* prow = pre + ((size_t)((b0+b)*1024 + t))*2048 + kb + kl0;
    short4v pg0 = *(const short4v*)&prow[0];
    short4v pg1 = *(const short4v*)&prow[512];
    short4v pg2 = *(const short4v*)&prow[1024];
    short4v pg3 = *(const short4v*)&prow[1536];
    f32x4 acc = {0.f,0.f,0.f,0.f};
    {
      int rb = l15*512;
#pragma unroll
      for (int s=0;s<16;s++){
        int ku = s*32 + l4*8;
        short8 a = *(const short8*)&hs[rb + (ku ^ ((l15&7)<<3))];
        acc = __builtin_amdgcn_mfma_f32_16x16x32_bf16(a, bf[s], acc, 0,0,0);
      }
    }
    {
      int rr = l4*4, rc = w*16 + l15;
#pragma unroll
      for (int i=0;i<4;i++) recb[(rr+i)*64 + rc] = acc[i];
    }
    __syncthreads();
    f32x4 rec4 = *(const f32x4*)&recb[b*64 + kl0];
    u32 tag = (u32)(epoch + t + 1) & 0xffffu;
    short4v hvv; f32x4 hfv;
#pragma unroll
    for (int j=0;j<4;j++){
      float r = rec4[j];
      float gi = sigm(bf2f((u16)pg0[j]) + r);
      float gf = sigm(bf2f((u16)pg1[j]) + r);
      float gg = sigm(bf2f((u16)pg2[j]) + r);
      float go = sigm(bf2f((u16)pg3[j]) + r);
      cv[j] = gf + cv[j] + gi*gg;
      float h = go + tanh_a(cv[j]);
      u16 hb = f2bf(h);
      hvv[j] = (short)hb;
      hfv[j] = h;
      __hip_atomic_store(&h_tag[(size_t)((t&1)*32 + b0 + b)*512 + kb + kl0 + j], (tag<<16)|(u32)hb,
                         __ATOMIC_RELAXED, __HIP_MEMORY_SCOPE_AGENT);
    }
    *(short4v*)&hv_out[((size_t)((b0+b)*1024 + t))*512 + kb + kl0] = hvv;
    if (is_last){
      *(f32x4*)&out[32768 + ((size_t)((b0+b)*1024 + t))*512 + kb + kl0] = hfv;
      if (t == 1023){
        *(f32x4*)&out[(size_t)(b0+b)*512 + kb + kl0] = hfv;
        *(f32x4*)&out[16384 + (size_t)(b0+b)*512 + kb + kl0] = cv;
      }
    }
    // gather full h
    {
      const u32* src = &h_tag[(size_t)((t&1)*32 + b0)*512];
      u32 v[32];
#pragma unroll
      for (int j=0;j<32;j++) v[j] = __hip_atomic_load(&src[b*512 + (tid&15) + 16*j], __ATOMIC_RELAXED, __HIP_MEMORY_SCOPE_AGENT);
      u32 done = 0;
      while (done != 0xffffffffu){
#pragma unroll
        for (int j=0;j<32;j++){
          if (!((done>>j)&1)){
            if ((v[j]>>16) == tag) done |= 1u<<j;
            else v[j] = __hip_atomic_load(&src[b*512 + (tid&15) + 16*j], __ATOMIC_RELAXED, __HIP_MEMORY_SCOPE_AGENT);
          }
        }
      }
#pragma unroll
      for (int j=0;j<32;j++){
        int k = (tid&15) + 16*j;
        hs[b*512 + (k ^ ((b&7)<<3))] = (u16)(v[j] & 0xffffu);
      }
    }
    __syncthreads();
  }
}

extern "C" void kernel_launch(void* const* d_in, const int* in_sizes, int n_in,
                              void* d_out, int out_size, void* d_ws, size_t ws_size,
                              hipStream_t stream)
{
  const float* x  = (const float*)d_in[0];
  const float* w1 = (const float*)d_in[1];
  const float* u1 = (const float*)d_in[2];
  const float* b1 = (const float*)d_in[3];
  const float* wx = (const float*)d_in[4];
  const float* wh = (const float*)d_in[5];
  const float* uv = (const float*)d_in[6];
  const float* bv = (const float*)d_in[7];
  float* out = (float*)d_out;

  char* p = (char*)d_ws;
  u16* pre  = (u16*)p; p += (size_t)134217728;   // [32768][2048] bf16
  u16* hvA  = (u16*)p; p += 33554432;            // [32][1024][512] bf16
  u16* hvB  = (u16*)p; p += 33554432;
  u16* xb   = (u16*)p; p += 33554432;            // [32768][512] bf16
  u16* w1p  = (u16*)p; p += 2097152;             // [2048][512] bf16
  u16* wxp  = (u16*)p; p += 6291456;             // 3x
  u16* whp  = (u16*)p; p += 6291456;             // 3x
  u16* u1p  = (u16*)p; p += 2097152;             // [4][512][512] bf16
  u16* uv0p = (u16*)p; p += 1572864;             // 3x [512][512] bf16
  u32* htag = (u32*)p; p += 131072;              // [2][32][512] u32
  if ((size_t)(p - (char*)d_ws) > ws_size) return; // ws too small: bail (will show as absmax fail)

  hipMemsetAsync(htag, 0, 131072, stream);
  cast_x_kernel<<<2048,256,0,stream>>>(x, xb);
  pack_w_kernel<<<2048,256,0,stream>>>(w1, wx, wh, w1p, wxp, whp);
  cast_u_kernel<<<1024,256,0,stream>>>(u1, uv, u1p, uv0p);

  gemm_pre_kernel<<<dim3(256,16),256,0,stream>>>(xb, w1p, (const u16*)nullptr, (const u16*)nullptr, b1, 2047, pre, 1);
  scan1_kernel<<<32,512,0,stream>>>(pre, u1p, hvA, htag);

  u16* hp = hvA; u16* hc = hvB;
  for (int l=0;l<3;l++){
    gemm_pre_kernel<<<dim3(256,16),256,0,stream>>>(xb, wxp + (size_t)l*1048576, hp, whp + (size_t)l*1048576,
                                                   bv + (size_t)l*2048, 511, pre, 2);
    scan2_kernel<<<16,256,0,stream>>>(pre, uv0p + (size_t)l*262144, hc, htag, 1024*(l+1), (l==2)?1:0, out);
    u16* tmp = hp; hp = hc; hc = tmp;
  }
}

// Round 3
// 19701.300 us; speedup vs baseline: 1.5696x; 1.5696x over previous
//
#include <hip/hip_runtime.h>

typedef unsigned short u16;
typedef unsigned int u32;
typedef unsigned long long u64;
typedef __attribute__((ext_vector_type(4))) float f32x4;
typedef __attribute__((ext_vector_type(8))) short short8;
typedef __attribute__((ext_vector_type(4))) short short4v;

__device__ __forceinline__ float bf2f(u16 v){ u32 b = ((u32)v)<<16; float f; __builtin_memcpy(&f,&b,4); return f; }
__device__ __forceinline__ u16 f2bf(float f){ u32 b; __builtin_memcpy(&b,&f,4); b = b + 0x7fffu + ((b>>16)&1u); return (u16)(b>>16); }
__device__ __forceinline__ float sigm(float x){ return 1.f/(1.f+__expf(-x)); }
__device__ __forceinline__ float tanh_a(float x){ return 1.f - 2.f/(__expf(2.f*x)+1.f); }

typedef const __attribute__((address_space(1))) u32* gas1;
typedef __attribute__((address_space(3))) u32* las3;
__device__ __forceinline__ void gld16(const u16* g, u16* l){
  __builtin_amdgcn_global_load_lds((gas1)g, (las3)l, 16, 0, 0);
}

// ---- proven exchange primitives (round-1): HIP relaxed agent-scope atomics ----
__device__ __forceinline__ void pub64(u32* p, u64 v){
  __hip_atomic_store((u64*)p, v, __ATOMIC_RELAXED, __HIP_MEMORY_SCOPE_AGENT);
}
__device__ __forceinline__ u64 pol64(const u32* p){
  return __hip_atomic_load((const u64*)p, __ATOMIC_RELAXED, __HIP_MEMORY_SCOPE_AGENT);
}
__device__ __forceinline__ u32 pol32(const u32* p){
  return __hip_atomic_load(p, __ATOMIC_RELAXED, __HIP_MEMORY_SCOPE_AGENT);
}

// ---------------- pack / cast kernels ----------------
__global__ void cast_x_kernel(const float* __restrict__ in, u16* __restrict__ out){
  int i = blockIdx.x*256 + threadIdx.x;
  for (; i < 4194304; i += 2048*256){
    f32x4 v = ((const f32x4*)in)[i];
    short4v o;
    o[0]=(short)f2bf(v[0]); o[1]=(short)f2bf(v[1]); o[2]=(short)f2bf(v[2]); o[3]=(short)f2bf(v[3]);
    ((short4v*)out)[i] = o;
  }
}

__global__ void pack_w_kernel(const float* __restrict__ w1, const float* __restrict__ wx, const float* __restrict__ wh,
                              u16* __restrict__ w1p, u16* __restrict__ wxp, u16* __restrict__ whp){
  int e = blockIdx.x*256 + threadIdx.x;
  for (; e < 7340032; e += 2048*256){
    int m = e >> 20; int r = e & 1048575;
    int h = r & 511, k = (r>>9)&511, g = r>>18;
    const float* src; u16* dst;
    if (m==0){ src=w1; dst=w1p; }
    else if (m<=3){ src = wx + (size_t)(m-1)*1048576; dst = wxp + (size_t)(m-1)*1048576; }
    else { src = wh + (size_t)(m-4)*1048576; dst = whp + (size_t)(m-4)*1048576; }
    dst[(size_t)(g*512 + h)*512 + k] = f2bf(src[(size_t)g*262144 + (size_t)k*512 + h]);
  }
}

__global__ void cast_u_kernel(const float* __restrict__ u1, const float* __restrict__ uv,
                              u16* __restrict__ u1p, u16* __restrict__ uv0p){
  int e = blockIdx.x*256 + threadIdx.x;
  for (; e < 1835008; e += 1024*256){
    if (e < 1048576) u1p[e] = f2bf(u1[e]);
    else { int r = e - 1048576; uv0p[r] = f2bf(uv[(size_t)(r>>18)*1048576 + (r & 262143)]); }
  }
}

// ---------------- GEMM: pre[bt,n] = sum_p A_p @ B_p^T + bias (unchanged, proven) ----------------
__global__ __launch_bounds__(256) void gemm_pre_kernel(
    const u16* __restrict__ A1, const u16* __restrict__ B1,
    const u16* __restrict__ A2, const u16* __restrict__ B2,
    const float* __restrict__ bias, int bmask,
    u16* __restrict__ Out, int nPass)
{
  __shared__ u16 As[128*64];
  __shared__ u16 Bs[128*64];
  const int tid = threadIdx.x;
  const int w = tid>>6, lane = tid&63;
  const int l15 = lane&15, l4 = lane>>4;
  const int m0 = blockIdx.x*128, n0 = blockIdx.y*128;
  const int wm = w>>1, wn = w&1;
  f32x4 acc[4][4];
#pragma unroll
  for (int a=0;a<4;a++)
#pragma unroll
    for (int bq=0;bq<4;bq++) acc[a][bq] = (f32x4){0.f,0.f,0.f,0.f};

  for (int p=0;p<nPass;p++){
    const u16* Ap = p ? A2 : A1;
    const u16* Bp = p ? B2 : B1;
    for (int kt=0;kt<8;kt++){
      const int k0 = kt*64;
      __syncthreads();
#pragma unroll
      for (int i=0;i<4;i++){
        int chunk = w*4 + i;
        int fb = chunk*1024 + lane*16;
        int row = fb>>7;
        int slot = (fb>>4)&7;
        const u16* srcA = Ap + (size_t)(m0+row)*512 + k0 + ((slot ^ (row&7))<<3);
        gld16(srcA, (u16*)As + chunk*512);
        const u16* srcB = Bp + (size_t)(n0+row)*512 + k0 + ((slot ^ (row&7))<<3);
        gld16(srcB, (u16*)Bs + chunk*512);
      }
      __syncthreads();
#pragma unroll
      for (int kk=0;kk<2;kk++){
        short8 af[4], bfq[4];
#pragma unroll
        for (int mi=0;mi<4;mi++){
          int row = wm*64 + mi*16 + l15;
          int s16 = l4 + kk*4;
          af[mi] = *(const short8*)&As[row*64 + ((s16 ^ (row&7))<<3)];
        }
#pragma unroll
        for (int ni=0;ni<4;ni++){
          int row = wn*64 + ni*16 + l15;
          int s16 = l4 + kk*4;
          bfq[ni] = *(const short8*)&Bs[row*64 + ((s16 ^ (row&7))<<3)];
        }
#pragma unroll
        for (int mi=0;mi<4;mi++)
#pragma unroll
          for (int ni=0;ni<4;ni++)
            acc[mi][ni] = __builtin_amdgcn_mfma_f32_16x16x32_bf16(af[mi], bfq[ni], acc[mi][ni], 0,0,0);
      }
    }
  }
#pragma unroll
  for (int ni=0;ni<4;ni++){
    int col = n0 + wn*64 + ni*16 + l15;
    float bb = bias[col & bmask];
#pragma unroll
    for (int mi=0;mi<4;mi++){
#pragma unroll
      for (int i=0;i<4;i++){
        int row = m0 + wm*64 + mi*16 + l4*4 + i;
        Out[(size_t)row*2048 + col] = f2bf(acc[mi][ni][i] + bb);
      }
    }
  }
}

// ---------------- scan layer 1 (4 distinct U gates) ----------------
// grid 16 = gb(2) x gk(8). 512 threads (8 waves). WG owns 64 h-cols (=256 rec cols
// across 4 gates) for 16 batches. Wave w: gate g=w>>1, col-half ch=w&1 -> 32 rec cols
// in registers (128 VGPR of B-frags).
__global__ __launch_bounds__(512,2) void scan1_kernel(
    const u16* __restrict__ pre, const u16* __restrict__ u1p,
    u16* __restrict__ hv_out, u32* h_tag)
{
  __shared__ u16 hs[16*512];       // [b][hcol] swizzled
  __shared__ float recb[16*256];   // [b][g*64 + local hcol]
  const int tid = threadIdx.x;
  const int wg = blockIdx.x;
  const int gk = wg & 7, gb = wg >> 3;
  const int b0 = gb*16, kb = gk*64;
  const int lane = tid&63, w = tid>>6;
  const int l15 = lane&15, l4 = lane>>4;
  const int g = w>>1, ch = w&1;

  short8 bfr[2][16];   // U1 slice resident: B[k][col], col = kb+ch*32+n*16+l15 of gate g
#pragma unroll
  for (int n=0;n<2;n++){
    const u16* up = u1p + (size_t)g*262144 + (kb + ch*32 + n*16 + l15);
#pragma unroll
    for (int s=0;s<16;s++){
      int kbase = s*32 + l4*8;
#pragma unroll
      for (int j=0;j<8;j++) bfr[n][s][j] = (short)up[(size_t)(kbase+j)*512];
    }
  }
  { short8 z = {0,0,0,0,0,0,0,0};
    for (int i=tid;i<1024;i+=512) ((short8*)hs)[i]=z; }
  const int b = tid>>5, q = tid&31;
  const int hc2 = q*2;             // own 2 h-cols: kb+hc2, kb+hc2+1
  float cA = 0.f, cB = 0.f;
  __syncthreads();

  for (int t=0;t<1024;++t){
    // pre loads (independent of h -> overlap)
    const u16* prow = pre + ((size_t)((b0+b)*1024+t))*2048 + kb + hc2;
    u32 pw0 = *(const u32*)(prow);
    u32 pw1 = *(const u32*)(prow+512);
    u32 pw2 = *(const u32*)(prow+1024);
    u32 pw3 = *(const u32*)(prow+1536);
    // rec = h @ U1 slice
    f32x4 acc0 = {0.f,0.f,0.f,0.f}, acc1 = {0.f,0.f,0.f,0.f};
    {
      int rb = l15*512, sw = (l15&7)<<3;
#pragma unroll
      for (int s=0;s<16;s++){
        short8 a = *(const short8*)&hs[rb + ((s*32 + l4*8) ^ sw)];
        acc0 = __builtin_amdgcn_mfma_f32_16x16x32_bf16(a, bfr[0][s], acc0, 0,0,0);
        acc1 = __builtin_amdgcn_mfma_f32_16x16x32_bf16(a, bfr[1][s], acc1, 0,0,0);
      }
    }
    {
      int base = g*64 + ch*32 + l15;
#pragma unroll
      for (int i=0;i<4;i++){
        recb[(l4*4+i)*256 + base]      = acc0[i];
        recb[(l4*4+i)*256 + base + 16] = acc1[i];
      }
    }
    __syncthreads();
    // gates: thread owns (b, 2 cols)
    float ri0 = recb[b*256 + hc2],       ri1 = recb[b*256 + hc2+1];
    float rf0 = recb[b*256 + 64 + hc2],  rf1 = recb[b*256 + 64 + hc2+1];
    float rg0 = recb[b*256 + 128 + hc2], rg1 = recb[b*256 + 128 + hc2+1];
    float ro0 = recb[b*256 + 192 + hc2], ro1 = recb[b*256 + 192 + hc2+1];
    float gi0 = sigm(bf2f((u16)(pw0&0xffffu)) + ri0), gi1 = sigm(bf2f((u16)(pw0>>16)) + ri1);
    float gf0 = sigm(bf2f((u16)(pw1&0xffffu)) + rf0), gf1 = sigm(bf2f((u16)(pw1>>16)) + rf1);
    float gg0 = sigm(bf2f((u16)(pw2&0xffffu)) + rg0), gg1 = sigm(bf2f((u16)(pw2>>16)) + rg1);
    float go0 = sigm(bf2f((u16)(pw3&0xffffu)) + ro0), go1 = sigm(bf2f((u16)(pw3>>16)) + ro1);
    cA = gf0 + cA + gi0*gg0; float h0v = go0 + tanh_a(cA);
    cB = gf1 + cB + gi1*gg1; float h1v = go1 + tanh_a(cB);
    u16 hb0 = f2bf(h0v), hb1 = f2bf(h1v);
    const u32 tag = (u32)(t+1);
    const size_t row = (size_t)((t&1)*32 + b0 + b);
    // publish FIRST (visibility-critical)
    u64 msg = (((u64)((tag<<16)|(u32)hb1))<<32) | (u64)((tag<<16)|(u32)hb0);
    pub64(&h_tag[row*512 + kb + hc2], msg);
    // own slice to LDS + hv_out
    u32 hpair = (u32)hb0 | ((u32)hb1<<16);
    *(u32*)&hs[b*512 + ((kb+hc2) ^ ((b&7)<<3))] = hpair;
    *(u32*)&hv_out[((size_t)((b0+b)*1024+t))*512 + kb + hc2] = hpair;
    // gather 448 foreign cols: 14 words/thread, batched unconditional rounds
    {
      const u32* src = &h_tag[row*512];
      u32 nv[14];
      for(;;){
#pragma unroll
        for (int j=0;j<14;j++){
          int fc = q*14 + j;
          int ac = fc + (fc>=kb ? 64 : 0);
          nv[j] = pol32(&src[ac]);
        }
        u32 ok = 0;
#pragma unroll
        for (int j=0;j<14;j++) if ((nv[j]>>16)==tag) ok |= 1u<<j;
        if (ok == 0x3fffu) break;
      }
#pragma unroll
      for (int j=0;j<14;j++){
        int fc = q*14 + j;
        int ac = fc + (fc>=kb ? 64 : 0);
        hs[b*512 + (ac ^ ((b&7)<<3))] = (u16)(nv[j]&0xffffu);
      }
    }
    __syncthreads();
  }
}

// ---------------- scan layers 2..4 (shared u[0], shared rec across gates) ----------------
// grid 4 = gb(2) x ch(2). 512 threads (8 waves). WG owns 256 cols for 16 batches;
// single exchange partner (the other col-half).
__global__ __launch_bounds__(512,2) void scan2_kernel(
    const u16* __restrict__ pre, const u16* __restrict__ u0p,
    u16* __restrict__ hv_out, u32* h_tag, int epoch, int is_last, float* __restrict__ out)
{
  __shared__ u16 hs[16*512];
  __shared__ float recb[16*256];
  const int tid = threadIdx.x;
  const int wg = blockIdx.x;
  const int ch = wg & 1, gb = wg >> 1;
  const int b0 = gb*16, cbase = ch*256;
  const int lane = tid&63, w = tid>>6;
  const int l15 = lane&15, l4 = lane>>4;

  short8 bfr[2][16];   // u0 slice: cols cbase + w*32 + n*16 + l15
#pragma unroll
  for (int n=0;n<2;n++){
    const u16* up = u0p + (cbase + w*32 + n*16 + l15);
#pragma unroll
    for (int s=0;s<16;s++){
      int kbase = s*32 + l4*8;
#pragma unroll
      for (int j=0;j<8;j++) bfr[n][s][j] = (short)up[(size_t)(kbase+j)*512];
    }
  }
  { short8 z = {0,0,0,0,0,0,0,0};
    for (int i=tid;i<1024;i+=512) ((short8*)hs)[i]=z; }
  const int b = tid>>5, q = tid&31;
  const int oc = cbase + q*8;       // own 8 cols (global col index)
  float cv[8];
#pragma unroll
  for (int j=0;j<8;j++) cv[j] = 0.f;
  __syncthreads();

  for (int t=0;t<1024;++t){
    const u16* prow = pre + ((size_t)((b0+b)*1024+t))*2048 + oc;
    short8 pg0 = *(const short8*)(prow);
    short8 pg1 = *(const short8*)(prow+512);
    short8 pg2 = *(const short8*)(prow+1024);
    short8 pg3 = *(const short8*)(prow+1536);
    f32x4 acc0 = {0.f,0.f,0.f,0.f}, acc1 = {0.f,0.f,0.f,0.f};
    {
      int rb = l15*512, sw = (l15&7)<<3;
#pragma unroll
      for (int s=0;s<16;s++){
        short8 a = *(const short8*)&hs[rb + ((s*32 + l4*8) ^ sw)];
        acc0 = __builtin_amdgcn_mfma_f32_16x16x32_bf16(a, bfr[0][s], acc0, 0,0,0);
        acc1 = __builtin_amdgcn_mfma_f32_16x16x32_bf16(a, bfr[1][s], acc1, 0,0,0);
      }
    }
    {
      int base = w*32 + l15;
#pragma unroll
      for (int i=0;i<4;i++){
        recb[(l4*4+i)*256 + base]      = acc0[i];
        recb[(l4*4+i)*256 + base + 16] = acc1[i];
      }
    }
    __syncthreads();
    const u32 tag = (u32)(epoch + t + 1);
    const size_t row = (size_t)((t&1)*32 + b0 + b);
    short8 hvv; float hf[8]; u32 msgw[8];
#pragma unroll
    for (int j=0;j<8;j++){
      float r = recb[b*256 + q*8 + j];
      float gi = sigm(bf2f((u16)pg0[j]) + r);
      float gf = sigm(bf2f((u16)pg1[j]) + r);
      float gg = sigm(bf2f((u16)pg2[j]) + r);
      float go = sigm(bf2f((u16)pg3[j]) + r);
      cv[j] = gf + cv[j] + gi*gg;
      float h = go + tanh_a(cv[j]);
      u16 hb = f2bf(h);
      hvv[j] = (short)hb;
      hf[j] = h;
      msgw[j] = (tag<<16)|(u32)hb;
    }
    // publish FIRST
#pragma unroll
    for (int j=0;j<4;j++){
      u64 m = (((u64)msgw[2*j+1])<<32) | (u64)msgw[2*j];
      pub64(&h_tag[row*512 + oc + 2*j], m);
    }
    // own slice to LDS + hv_out
    *(short8*)&hs[b*512 + (oc ^ ((b&7)<<3))] = hvv;
    *(short8*)&hv_out[((size_t)((b0+b)*1024+t))*512 + oc] = hvv;
    if (is_last){
      f32x4 h4a = {hf[0],hf[1],hf[2],hf[3]}, h4b = {hf[4],hf[5],hf[6],hf[7]};
      *(f32x4*)&out[32768 + ((size_t)((b0+b)*1024+t))*512 + oc]     = h4a;
      *(f32x4*)&out[32768 + ((size_t)((b0+b)*1024+t))*512 + oc + 4] = h4b;
      if (t == 1023){
        *(f32x4*)&out[(size_t)(b0+b)*512 + oc]     = h4a;
        *(f32x4*)&out[(size_t)(b0+b)*512 + oc + 4] = h4b;
        f32x4 c4a = {cv[0],cv[1],cv[2],cv[3]}, c4b = {cv[4],cv[5],cv[6],cv[7]};
        *(f32x4*)&out[16384 + (size_t)(b0+b)*512 + oc]     = c4a;
        *(f32x4*)&out[16384 + (size_t)(b0+b)*512 + oc + 4] = c4b;
      }
    }
    // gather single partner's 256 cols: 8 words (4 u64) per thread
    {
      const u32* src = &h_tag[row*512 + ((ch^1)*256 + q*8)];
      u64 nv[4];
      for(;;){
#pragma unroll
        for (int j=0;j<4;j++) nv[j] = pol64(&src[2*j]);
        u32 ok = 0;
#pragma unroll
        for (int j=0;j<4;j++){
          if ((u32)(((u32)nv[j])>>16) == tag) ok |= 1u<<(2*j);
          if ((u32)(nv[j]>>48) == tag)        ok |= 1u<<(2*j+1);
        }
        if (ok == 0xffu) break;
      }
      short8 hh;
#pragma unroll
      for (int j=0;j<4;j++){
        hh[2*j]   = (short)(u16)(nv[j] & 0xffffu);
        hh[2*j+1] = (short)(u16)((nv[j]>>32) & 0xffffu);
      }
      int pc = (ch^1)*256 + q*8;
      *(short8*)&hs[b*512 + (pc ^ ((b&7)<<3))] = hh;
    }
    __syncthreads();
  }
}

extern "C" void kernel_launch(void* const* d_in, const int* in_sizes, int n_in,
                              void* d_out, int out_size, void* d_ws, size_t ws_size,
                              hipStream_t stream)
{
  const float* x  = (const float*)d_in[0];
  const float* w1 = (const float*)d_in[1];
  const float* u1 = (const float*)d_in[2];
  const float* b1 = (const float*)d_in[3];
  const float* wx = (const float*)d_in[4];
  const float* wh = (const float*)d_in[5];
  const float* uv = (const float*)d_in[6];
  const float* bv = (const float*)d_in[7];
  float* out = (float*)d_out;

  char* p = (char*)d_ws;
  u16* pre  = (u16*)p; p += (size_t)134217728;   // [32768][2048] bf16
  u16* hvA  = (u16*)p; p += 33554432;            // [32][1024][512] bf16
  u16* hvB  = (u16*)p; p += 33554432;
  u16* xb   = (u16*)p; p += 33554432;            // [32768][512] bf16
  u16* w1p  = (u16*)p; p += 2097152;
  u16* wxp  = (u16*)p; p += 6291456;
  u16* whp  = (u16*)p; p += 6291456;
  u16* u1p  = (u16*)p; p += 2097152;
  u16* uv0p = (u16*)p; p += 1572864;
  u32* htag = (u32*)p; p += 131072;              // [2][32][512] u32
  if ((size_t)(p - (char*)d_ws) > ws_size) return;

  hipMemsetAsync(htag, 0, 131072, stream);
  cast_x_kernel<<<2048,256,0,stream>>>(x, xb);
  pack_w_kernel<<<2048,256,0,stream>>>(w1, wx, wh, w1p, wxp, whp);
  cast_u_kernel<<<1024,256,0,stream>>>(u1, uv, u1p, uv0p);

  gemm_pre_kernel<<<dim3(256,16),256,0,stream>>>(xb, w1p, (const u16*)nullptr, (const u16*)nullptr, b1, 2047, pre, 1);
  scan1_kernel<<<16,512,0,stream>>>(pre, u1p, hvA, htag);

  u16* hp = hvA; u16* hc = hvB;
  for (int l=0;l<3;l++){
    gemm_pre_kernel<<<dim3(256,16),256,0,stream>>>(xb, wxp + (size_t)l*1048576, hp, whp + (size_t)l*1048576,
                                                   bv + (size_t)l*2048, 511, pre, 2);
    scan2_kernel<<<4,512,0,stream>>>(pre, uv0p + (size_t)l*262144, hc, htag, 1024*(l+1), (l==2)?1:0, out);
    u16* tmp = hp; hp = hc; hc = tmp;
  }
}

// Round 4
// 10793.085 us; speedup vs baseline: 2.8650x; 1.8254x over previous
//
#include <hip/hip_runtime.h>

typedef unsigned short u16;
typedef unsigned int u32;
typedef unsigned long long u64;
typedef __attribute__((ext_vector_type(4))) float f32x4;
typedef __attribute__((ext_vector_type(8))) short short8;
typedef __attribute__((ext_vector_type(4))) short short4v;

__device__ __forceinline__ float bf2f(u16 v){ u32 b = ((u32)v)<<16; float f; __builtin_memcpy(&f,&b,4); return f; }
__device__ __forceinline__ u16 f2bf(float f){ u32 b; __builtin_memcpy(&b,&f,4); b = b + 0x7fffu + ((b>>16)&1u); return (u16)(b>>16); }
__device__ __forceinline__ float sigm(float x){ return 1.f/(1.f+__expf(-x)); }
__device__ __forceinline__ float tanh_a(float x){ return 1.f - 2.f/(__expf(2.f*x)+1.f); }
__device__ __forceinline__ int imin(int a, int b){ return a<b?a:b; }

typedef const __attribute__((address_space(1))) u32* gas1;
typedef __attribute__((address_space(3))) u32* las3;
__device__ __forceinline__ void gld16(const u16* g, u16* l){
  __builtin_amdgcn_global_load_lds((gas1)g, (las3)l, 16, 0, 0);
}

// ---- proven exchange primitives: HIP relaxed agent-scope atomics ----
__device__ __forceinline__ void pub64(u32* p, u64 v){
  __hip_atomic_store((u64*)p, v, __ATOMIC_RELAXED, __HIP_MEMORY_SCOPE_AGENT);
}
__device__ __forceinline__ void pub32(u32* p, u32 v){
  __hip_atomic_store(p, v, __ATOMIC_RELAXED, __HIP_MEMORY_SCOPE_AGENT);
}
__device__ __forceinline__ u64 pol64(const u32* p){
  return __hip_atomic_load((const u64*)p, __ATOMIC_RELAXED, __HIP_MEMORY_SCOPE_AGENT);
}
__device__ __forceinline__ u32 pol32(const u32* p){
  return __hip_atomic_load(p, __ATOMIC_RELAXED, __HIP_MEMORY_SCOPE_AGENT);
}

// ---------------- pack / cast kernels ----------------
__global__ void cast_x_kernel(const float* __restrict__ in, u16* __restrict__ out){
  int i = blockIdx.x*256 + threadIdx.x;
  for (; i < 4194304; i += 2048*256){
    f32x4 v = ((const f32x4*)in)[i];
    short4v o;
    o[0]=(short)f2bf(v[0]); o[1]=(short)f2bf(v[1]); o[2]=(short)f2bf(v[2]); o[3]=(short)f2bf(v[3]);
    ((short4v*)out)[i] = o;
  }
}

// w1[4,512,512] -> w1p[n=g*512+h][k]; wx/wh -> wxwhp[lv][n=g*512+h][k(1024): k<512 wx, else wh]
__global__ void pack_w_kernel(const float* __restrict__ w1, const float* __restrict__ wx, const float* __restrict__ wh,
                              u16* __restrict__ w1p, u16* __restrict__ wxwhp){
  int e = blockIdx.x*256 + threadIdx.x;
  for (; e < 7340032; e += 2048*256){
    if (e < 1048576){
      int h = e & 511, k = (e>>9)&511, g = e>>18;
      w1p[(size_t)(g*512+h)*512 + k] = f2bf(w1[(size_t)g*262144 + (size_t)k*512 + h]);
    } else {
      int r = e - 1048576;
      int lv = r >> 21;
      int q = r & 2097151;
      int n = q >> 10, k = q & 1023;
      int g = n >> 9, h = n & 511;
      float v;
      if (k < 512) v = wx[(size_t)lv*1048576 + (size_t)g*262144 + (size_t)k*512 + h];
      else         v = wh[(size_t)lv*1048576 + (size_t)g*262144 + (size_t)(k-512)*512 + h];
      wxwhp[(size_t)lv*2097152 + (size_t)n*1024 + k] = f2bf(v);
    }
  }
}

__global__ void cast_u_kernel(const float* __restrict__ u1, const float* __restrict__ uv,
                              u16* __restrict__ u1p, u16* __restrict__ uv0p){
  int e = blockIdx.x*256 + threadIdx.x;
  for (; e < 1835008; e += 1024*256){
    if (e < 1048576) u1p[e] = f2bf(u1[e]);
    else { int r = e - 1048576; uv0p[r] = f2bf(uv[(size_t)(r>>18)*1048576 + (r & 262143)]); }
  }
}

// ---------------- GEMM: pre1[bt,n] = xb @ w1p^T + b1 (proven) ----------------
__global__ __launch_bounds__(256) void gemm_pre_kernel(
    const u16* __restrict__ A1, const u16* __restrict__ B1,
    const u16* __restrict__ A2, const u16* __restrict__ B2,
    const float* __restrict__ bias, int bmask,
    u16* __restrict__ Out, int nPass)
{
  __shared__ u16 As[128*64];
  __shared__ u16 Bs[128*64];
  const int tid = threadIdx.x;
  const int w = tid>>6, lane = tid&63;
  const int l15 = lane&15, l4 = lane>>4;
  const int m0 = blockIdx.x*128, n0 = blockIdx.y*128;
  const int wm = w>>1, wn = w&1;
  f32x4 acc[4][4];
#pragma unroll
  for (int a=0;a<4;a++)
#pragma unroll
    for (int bq=0;bq<4;bq++) acc[a][bq] = (f32x4){0.f,0.f,0.f,0.f};

  for (int p=0;p<nPass;p++){
    const u16* Ap = p ? A2 : A1;
    const u16* Bp = p ? B2 : B1;
    for (int kt=0;kt<8;kt++){
      const int k0 = kt*64;
      __syncthreads();
#pragma unroll
      for (int i=0;i<4;i++){
        int chunk = w*4 + i;
        int fb = chunk*1024 + lane*16;
        int row = fb>>7;
        int slot = (fb>>4)&7;
        const u16* srcA = Ap + (size_t)(m0+row)*512 + k0 + ((slot ^ (row&7))<<3);
        gld16(srcA, (u16*)As + chunk*512);
        const u16* srcB = Bp + (size_t)(n0+row)*512 + k0 + ((slot ^ (row&7))<<3);
        gld16(srcB, (u16*)Bs + chunk*512);
      }
      __syncthreads();
#pragma unroll
      for (int kk=0;kk<2;kk++){
        short8 af[4], bfq[4];
#pragma unroll
        for (int mi=0;mi<4;mi++){
          int row = wm*64 + mi*16 + l15;
          int s16 = l4 + kk*4;
          af[mi] = *(const short8*)&As[row*64 + ((s16 ^ (row&7))<<3)];
        }
#pragma unroll
        for (int ni=0;ni<4;ni++){
          int row = wn*64 + ni*16 + l15;
          int s16 = l4 + kk*4;
          bfq[ni] = *(const short8*)&Bs[row*64 + ((s16 ^ (row&7))<<3)];
        }
#pragma unroll
        for (int mi=0;mi<4;mi++)
#pragma unroll
          for (int ni=0;ni<4;ni++)
            acc[mi][ni] = __builtin_amdgcn_mfma_f32_16x16x32_bf16(af[mi], bfq[ni], acc[mi][ni], 0,0,0);
      }
    }
  }
#pragma unroll
  for (int ni=0;ni<4;ni++){
    int col = n0 + wn*64 + ni*16 + l15;
    float bb = bias[col & bmask];
#pragma unroll
    for (int mi=0;mi<4;mi++){
#pragma unroll
      for (int i=0;i<4;i++){
        int row = m0 + wm*64 + mi*16 + l4*4 + i;
        Out[(size_t)row*2048 + col] = f2bf(acc[mi][ni][i] + bb);
      }
    }
  }
}

// ================ fused pipelined megakernel ================
// blocks 0..15   : scan layer 0 (custom LSTM, 4 distinct U gates)   [16 WG]
// blocks 16..27  : scan layers 1..3 (VLSTM, shared u[0])            [4 WG each]
// blocks 28..123 : pre clusters for layers 1..3 ([x:h_prev]@[wx;wh])[32 WG each]
// hring[l] : 64-slot ring of tagged h words  [64][32][512] u32 per layer (4 layers)
// pring[lv]: 64-slot ring of tagged pre words [64][32][2048] u32 (3 layers)
// prog[(l-1)*4+sub]: scan layer l (1..3) progress counters (backpressure)
__global__ __launch_bounds__(512,2) void mega_kernel(
    const u16* __restrict__ pre1, const u16* __restrict__ u1p,
    const u16* __restrict__ uv0p, const u16* __restrict__ xb,
    const u16* __restrict__ wxwhp, const float* __restrict__ bv,
    u32* hring, u32* pring, u32* prog, float* __restrict__ out)
{
  __shared__ char smem[33024];
  const int bid = blockIdx.x;
  const int tid = threadIdx.x;
  const int lane = tid&63, w = tid>>6;
  const int l15 = lane&15, l4 = lane>>4;

  if (bid < 16){
    // ======== scan layer 0 (round-3 scan1, ring-ified) ========
    u16* hs = (u16*)smem;
    float* recb = (float*)(smem+16384);
    const int gk = bid & 7, gb = bid >> 3;
    const int b0 = gb*16, kb = gk*64;
    const int g = w>>1, ch = w&1;
    short8 bfr[2][16];
#pragma unroll
    for (int n=0;n<2;n++){
      const u16* up = u1p + (size_t)g*262144 + (kb + ch*32 + n*16 + l15);
#pragma unroll
      for (int s=0;s<16;s++){
        int kbase = s*32 + l4*8;
#pragma unroll
        for (int j=0;j<8;j++) bfr[n][s][j] = (short)up[(size_t)(kbase+j)*512];
      }
    }
    { short8 z = {0,0,0,0,0,0,0,0};
      for (int i=tid;i<1024;i+=512) ((short8*)hs)[i]=z; }
    const int b = tid>>5, q = tid&31;
    const int hc2 = q*2;
    float cA=0.f, cB=0.f;
    __syncthreads();

    for (int t=0;t<1024;++t){
      if ((t&15)==0 && t>=32){
        int thr = t-32;
        for(;;){
          int m0=(int)pol32(&prog[0]); m0=imin(m0,(int)pol32(&prog[1]));
          m0=imin(m0,(int)pol32(&prog[2])); m0=imin(m0,(int)pol32(&prog[3]));
          if (m0>=thr) break;
        }
      }
      const u16* prow = pre1 + ((size_t)((b0+b)*1024+t))*2048 + kb + hc2;
      u32 pw0 = *(const u32*)(prow);
      u32 pw1 = *(const u32*)(prow+512);
      u32 pw2 = *(const u32*)(prow+1024);
      u32 pw3 = *(const u32*)(prow+1536);
      f32x4 acc0 = {0.f,0.f,0.f,0.f}, acc1 = {0.f,0.f,0.f,0.f};
      {
        int rb = l15*512, sw = (l15&7)<<3;
#pragma unroll
        for (int s=0;s<16;s++){
          short8 a = *(const short8*)&hs[rb + ((s*32 + l4*8) ^ sw)];
          acc0 = __builtin_amdgcn_mfma_f32_16x16x32_bf16(a, bfr[0][s], acc0, 0,0,0);
          acc1 = __builtin_amdgcn_mfma_f32_16x16x32_bf16(a, bfr[1][s], acc1, 0,0,0);
        }
      }
      {
        int base = g*64 + ch*32 + l15;
#pragma unroll
        for (int i=0;i<4;i++){
          recb[(l4*4+i)*256 + base]      = acc0[i];
          recb[(l4*4+i)*256 + base + 16] = acc1[i];
        }
      }
      __syncthreads();
      float ri0 = recb[b*256 + hc2],       ri1 = recb[b*256 + hc2+1];
      float rf0 = recb[b*256 + 64 + hc2],  rf1 = recb[b*256 + 64 + hc2+1];
      float rg0 = recb[b*256 + 128 + hc2], rg1 = recb[b*256 + 128 + hc2+1];
      float ro0 = recb[b*256 + 192 + hc2], ro1 = recb[b*256 + 192 + hc2+1];
      float gi0 = sigm(bf2f((u16)(pw0&0xffffu)) + ri0), gi1 = sigm(bf2f((u16)(pw0>>16)) + ri1);
      float gf0 = sigm(bf2f((u16)(pw1&0xffffu)) + rf0), gf1 = sigm(bf2f((u16)(pw1>>16)) + rf1);
      float gg0 = sigm(bf2f((u16)(pw2&0xffffu)) + rg0), gg1 = sigm(bf2f((u16)(pw2>>16)) + rg1);
      float go0 = sigm(bf2f((u16)(pw3&0xffffu)) + ro0), go1 = sigm(bf2f((u16)(pw3>>16)) + ro1);
      cA = gf0 + cA + gi0*gg0; float h0v = go0 + tanh_a(cA);
      cB = gf1 + cB + gi1*gg1; float h1v = go1 + tanh_a(cB);
      u16 hb0 = f2bf(h0v), hb1 = f2bf(h1v);
      const u32 tag = (u32)(t+1);
      u32* slot = hring + (size_t)(t&63)*16384;
      u64 msg = (((u64)((tag<<16)|(u32)hb1))<<32) | (u64)((tag<<16)|(u32)hb0);
      pub64(&slot[(size_t)(b0+b)*512 + kb + hc2], msg);
      u32 hpair = (u32)hb0 | ((u32)hb1<<16);
      *(u32*)&hs[b*512 + ((kb+hc2) ^ ((b&7)<<3))] = hpair;
      // gather 448 foreign cols (14 words/thread, batched rounds)
      {
        const u32* srcg = slot + (size_t)(b0+b)*512;
        u32 nv[14];
        for(;;){
#pragma unroll
          for (int j=0;j<14;j++){
            int fc = q*14 + j;
            int ac = fc + (fc>=kb ? 64 : 0);
            nv[j] = pol32(&srcg[ac]);
          }
          u32 okm = 0;
#pragma unroll
          for (int j=0;j<14;j++) if ((nv[j]>>16)==tag) okm |= 1u<<j;
          if (okm == 0x3fffu) break;
        }
#pragma unroll
        for (int j=0;j<14;j++){
          int fc = q*14 + j;
          int ac = fc + (fc>=kb ? 64 : 0);
          hs[b*512 + (ac ^ ((b&7)<<3))] = (u16)(nv[j]&0xffffu);
        }
      }
      __syncthreads();
    }
  } else if (bid < 28){
    // ======== scan layers 1..3 (round-3 scan2, ring + polled pre) ========
    u16* hs = (u16*)smem;
    float* recb = (float*)(smem+16384);
    const int l = 1 + ((bid-16)>>2);
    const int lv = l-1;
    const int sub = (bid-16)&3;
    const int ch = sub&1, gb = sub>>1;
    const int b0 = gb*16, cbase = ch*256;
    short8 bfr[2][16];
#pragma unroll
    for (int n=0;n<2;n++){
      const u16* up = uv0p + (size_t)lv*262144 + (cbase + w*32 + n*16 + l15);
#pragma unroll
      for (int s=0;s<16;s++){
        int kbase = s*32 + l4*8;
#pragma unroll
        for (int j=0;j<8;j++) bfr[n][s][j] = (short)up[(size_t)(kbase+j)*512];
      }
    }
    { short8 z = {0,0,0,0,0,0,0,0};
      for (int i=tid;i<1024;i+=512) ((short8*)hs)[i]=z; }
    const int b = tid>>5, q = tid&31;
    const int oc = cbase + q*8;
    float cv[8];
#pragma unroll
    for (int j=0;j<8;j++) cv[j]=0.f;
    u32* hr = hring + (size_t)l*1048576;
    u32* pr = pring + (size_t)lv*4194304;
    const int is_last = (l==3);
    __syncthreads();

    for (int t=0;t<1024;++t){
      const u32 tag = (u32)(t+1);
      if (l<3 && (t&15)==0 && t>=32){
        int thr=t-32;
        const int pbase = l*4;
        for(;;){
          int m0=(int)pol32(&prog[pbase]); m0=imin(m0,(int)pol32(&prog[pbase+1]));
          m0=imin(m0,(int)pol32(&prog[pbase+2])); m0=imin(m0,(int)pol32(&prog[pbase+3]));
          if (m0>=thr) break;
        }
      }
      // recurrent MFMA first (needs only hs from t-1)
      f32x4 acc0={0.f,0.f,0.f,0.f}, acc1={0.f,0.f,0.f,0.f};
      {
        int rb=l15*512, sw=(l15&7)<<3;
#pragma unroll
        for (int s=0;s<16;s++){
          short8 a = *(const short8*)&hs[rb + ((s*32+l4*8)^sw)];
          acc0 = __builtin_amdgcn_mfma_f32_16x16x32_bf16(a, bfr[0][s], acc0, 0,0,0);
          acc1 = __builtin_amdgcn_mfma_f32_16x16x32_bf16(a, bfr[1][s], acc1, 0,0,0);
        }
      }
      {
        int base = w*32 + l15;
#pragma unroll
        for (int i=0;i<4;i++){
          recb[(l4*4+i)*256 + base]    = acc0[i];
          recb[(l4*4+i)*256 + base+16] = acc1[i];
        }
      }
      // poll pre (32 words = 16 u64), batched rounds
      u64 pv[16];
      {
        const u32* ps = pr + (size_t)(t&63)*65536 + (size_t)(b0+b)*2048;
        for(;;){
#pragma unroll
          for (int gq=0;gq<4;gq++)
#pragma unroll
            for (int j=0;j<4;j++)
              pv[gq*4+j] = pol64(&ps[gq*512 + oc + 2*j]);
          u32 ok=1;
#pragma unroll
          for (int i=0;i<16;i++){
            if ((u32)(((u32)pv[i])>>16) != tag) ok=0;
            if ((u32)(pv[i]>>48) != tag) ok=0;
          }
          if (ok) break;
        }
      }
      __syncthreads();
      short8 hvv; float hf[8]; u32 msgw[8];
#pragma unroll
      for (int j=0;j<8;j++){
        float r = recb[b*256 + q*8 + j];
        int wi = j>>1;
        u32 w0 = (j&1) ? (u32)(pv[wi]>>32)    : (u32)pv[wi];
        u32 w1v= (j&1) ? (u32)(pv[4+wi]>>32)  : (u32)pv[4+wi];
        u32 w2 = (j&1) ? (u32)(pv[8+wi]>>32)  : (u32)pv[8+wi];
        u32 w3 = (j&1) ? (u32)(pv[12+wi]>>32) : (u32)pv[12+wi];
        float gi = sigm(bf2f((u16)(w0&0xffffu)) + r);
        float gf = sigm(bf2f((u16)(w1v&0xffffu)) + r);
        float gg = sigm(bf2f((u16)(w2&0xffffu)) + r);
        float go = sigm(bf2f((u16)(w3&0xffffu)) + r);
        cv[j] = gf + cv[j] + gi*gg;
        float h = go + tanh_a(cv[j]);
        u16 hb = f2bf(h);
        hvv[j]=(short)hb; hf[j]=h; msgw[j] = (tag<<16)|(u32)hb;
      }
      u32* hslot = hr + (size_t)(t&63)*16384 + (size_t)(b0+b)*512;
#pragma unroll
      for (int j=0;j<4;j++){
        u64 m = (((u64)msgw[2*j+1])<<32) | (u64)msgw[2*j];
        pub64(&hslot[oc + 2*j], m);
      }
      *(short8*)&hs[b*512 + (oc ^ ((b&7)<<3))] = hvv;
      if (is_last){
        f32x4 h4a={hf[0],hf[1],hf[2],hf[3]}, h4b={hf[4],hf[5],hf[6],hf[7]};
        *(f32x4*)&out[32768 + ((size_t)((b0+b)*1024+t))*512 + oc]   = h4a;
        *(f32x4*)&out[32768 + ((size_t)((b0+b)*1024+t))*512 + oc+4] = h4b;
        if (t==1023){
          *(f32x4*)&out[(size_t)(b0+b)*512 + oc]   = h4a;
          *(f32x4*)&out[(size_t)(b0+b)*512 + oc+4] = h4b;
          f32x4 c4a={cv[0],cv[1],cv[2],cv[3]}, c4b={cv[4],cv[5],cv[6],cv[7]};
          *(f32x4*)&out[16384 + (size_t)(b0+b)*512 + oc]   = c4a;
          *(f32x4*)&out[16384 + (size_t)(b0+b)*512 + oc+4] = c4b;
        }
      }
      // partner gather (other 256-col half)
      {
        const u32* src = hslot + (ch^1)*256 + q*8;
        u64 nv[4];
        for(;;){
#pragma unroll
          for (int j=0;j<4;j++) nv[j] = pol64(&src[2*j]);
          u32 ok=1;
#pragma unroll
          for (int j=0;j<4;j++){
            if ((u32)(((u32)nv[j])>>16)!=tag) ok=0;
            if ((u32)(nv[j]>>48)!=tag) ok=0;
          }
          if (ok) break;
        }
        short8 hh;
#pragma unroll
        for (int j=0;j<4;j++){
          hh[2*j]   = (short)(u16)(nv[j] & 0xffffu);
          hh[2*j+1] = (short)(u16)((nv[j]>>32) & 0xffffu);
        }
        int pc = (ch^1)*256 + q*8;
        *(short8*)&hs[b*512 + (pc ^ ((b&7)<<3))] = hh;
      }
      __syncthreads();
      if (tid==0) pub32(&prog[(l-1)*4 + sub], (u32)(t+1));
    }
  } else {
    // ======== pre clusters: pre[t] = [x[t] : h_prev[t]] @ B^T + b0 ========
    u16* hstage = (u16*)smem;  // [32][512] bf16, XOR-swizzled
    const int lv = (bid-28)>>5;
    const int wgid = (bid-28)&31;
    const int rt = w&1, ct = w>>1;
    const int c = wgid*64 + ct*16 + l15;          // output col 0..2047
    const u16* Bw = wxwhp + (size_t)lv*2097152 + (size_t)c*1024;
    short8 bfr[32];
#pragma unroll
    for (int s=0;s<32;s++){
#pragma unroll
      for (int j=0;j<8;j++) bfr[s][j] = (short)Bw[s*32 + l4*8 + j];
    }
    const float bias = bv[lv*2048 + (c&511)];
    const int pb = tid>>4;                        // poll batch 0..31
    const int pk0 = (tid&15)*32;                  // poll k-base
    const u32* hr = hring + (size_t)lv*1048576;   // reads h of layer lv (= scan layer lv)
    u32* pr = pring + (size_t)lv*4194304;         // feeds scan layer lv+1
    const int bb = rt*16 + l15;                   // A row (batch)
    const int swr = (bb&7)<<3;
    const int sww = (pb&7)<<3;

    for (int t=0;t<1024;++t){
      const u32 tag = (u32)(t+1);
      f32x4 acc = {0.f,0.f,0.f,0.f};
      // x-part MFMAs (independent of h) overlap the h wait
      const u16* xrow = xb + ((size_t)bb*1024 + t)*512;
#pragma unroll
      for (int s=0;s<16;s++){
        short8 a = *(const short8*)&xrow[s*32 + l4*8];
        acc = __builtin_amdgcn_mfma_f32_16x16x32_bf16(a, bfr[s], acc, 0,0,0);
      }
      // poll h_prev[t] cooperatively (32 words/thread as 16 u64)
      {
        const u32* src = hr + (size_t)(t&63)*16384 + (size_t)pb*512 + pk0;
        u64 nv[16];
        for(;;){
#pragma unroll
          for (int j=0;j<16;j++) nv[j] = pol64(&src[2*j]);
          u32 ok=1;
#pragma unroll
          for (int j=0;j<16;j++){
            if ((u32)(((u32)nv[j])>>16)!=tag) ok=0;
            if ((u32)(nv[j]>>48)!=tag) ok=0;
          }
          if (ok) break;
        }
#pragma unroll
        for (int j=0;j<16;j++){
          u32 pair = ((u32)nv[j] & 0xffffu) | (((u32)(nv[j]>>32) & 0xffffu) << 16);
          int k = pk0 + 2*j;
          *(u32*)&hstage[(size_t)pb*512 + (k ^ sww)] = pair;
        }
      }
      __syncthreads();
      // h-part MFMAs
#pragma unroll
      for (int s=0;s<16;s++){
        short8 a = *(const short8*)&hstage[(size_t)bb*512 + ((s*32 + l4*8) ^ swr)];
        acc = __builtin_amdgcn_mfma_f32_16x16x32_bf16(a, bfr[16+s], acc, 0,0,0);
      }
      // publish pre (tagged per word)
      u32* dst = pr + (size_t)(t&63)*65536 + c;
#pragma unroll
      for (int i=0;i<4;i++){
        int bo = rt*16 + l4*4 + i;
        u32 v = ((u32)f2bf(acc[i]+bias)) | (tag<<16);
        pub32(&dst[(size_t)bo*2048], v);
      }
      __syncthreads();
    }
  }
}

extern "C" void kernel_launch(void* const* d_in, const int* in_sizes, int n_in,
                              void* d_out, int out_size, void* d_ws, size_t ws_size,
                              hipStream_t stream)
{
  const float* x  = (const float*)d_in[0];
  const float* w1 = (const float*)d_in[1];
  const float* u1 = (const float*)d_in[2];
  const float* b1 = (const float*)d_in[3];
  const float* wx = (const float*)d_in[4];
  const float* wh = (const float*)d_in[5];
  const float* uv = (const float*)d_in[6];
  const float* bv = (const float*)d_in[7];
  float* out = (float*)d_out;

  char* p = (char*)d_ws;
  u16* pre1  = (u16*)p; p += (size_t)134217728;  // [32768][2048] bf16
  u16* xb    = (u16*)p; p += 33554432;           // [32768][512] bf16
  u16* w1p   = (u16*)p; p += 2097152;            // [2048][512] bf16
  u16* wxwhp = (u16*)p; p += 12582912;           // 3 x [2048][1024] bf16
  u16* u1p   = (u16*)p; p += 2097152;            // [4][512][512] bf16
  u16* uv0p  = (u16*)p; p += 1572864;            // 3 x [512][512] bf16
  u32* hring = (u32*)p; p += 16777216;           // 4 x [64][32][512] u32
  u32* pring = (u32*)p; p += 50331648;           // 3 x [64][32][2048] u32
  u32* prog  = (u32*)p; p += 256;
  if ((size_t)(p - (char*)d_ws) > ws_size) return;

  hipMemsetAsync(hring, 0, 16777216, stream);
  hipMemsetAsync(pring, 0, 50331648, stream);
  hipMemsetAsync(prog, 0, 256, stream);
  cast_x_kernel<<<2048,256,0,stream>>>(x, xb);
  pack_w_kernel<<<2048,256,0,stream>>>(w1, wx, wh, w1p, wxwhp);
  cast_u_kernel<<<1024,256,0,stream>>>(u1, uv, u1p, uv0p);

  gemm_pre_kernel<<<dim3(256,16),256,0,stream>>>(xb, w1p, (const u16*)nullptr, (const u16*)nullptr, b1, 2047, pre1, 1);
  mega_kernel<<<124,512,0,stream>>>(pre1, u1p, uv0p, xb, wxwhp, bv, hring, pring, prog, out);
}

// Round 5
// 8042.106 us; speedup vs baseline: 3.8451x; 1.3421x over previous
//
#include <hip/hip_runtime.h>

typedef unsigned short u16;
typedef unsigned int u32;
typedef unsigned long long u64;
typedef __attribute__((ext_vector_type(4))) float f32x4;
typedef __attribute__((ext_vector_type(8))) short short8;
typedef __attribute__((ext_vector_type(4))) short short4v;

__device__ __forceinline__ float bf2f(u16 v){ u32 b = ((u32)v)<<16; float f; __builtin_memcpy(&f,&b,4); return f; }
__device__ __forceinline__ u16 f2bf(float f){ u32 b; __builtin_memcpy(&b,&f,4); b = b + 0x7fffu + ((b>>16)&1u); return (u16)(b>>16); }
__device__ __forceinline__ float sigm(float x){ return 1.f/(1.f+__expf(-x)); }
__device__ __forceinline__ float tanh_a(float x){ return 1.f - 2.f/(__expf(2.f*x)+1.f); }
__device__ __forceinline__ int imin(int a, int b){ return a<b?a:b; }

typedef const __attribute__((address_space(1))) u32* gas1;
typedef __attribute__((address_space(3))) u32* las3;
__device__ __forceinline__ void gld16(const u16* g, u16* l){
  __builtin_amdgcn_global_load_lds((gas1)g, (las3)l, 16, 0, 0);
}

// ---- proven exchange primitives: HIP relaxed agent-scope atomics ----
__device__ __forceinline__ void pub64(u32* p, u64 v){
  __hip_atomic_store((u64*)p, v, __ATOMIC_RELAXED, __HIP_MEMORY_SCOPE_AGENT);
}
__device__ __forceinline__ void pub32(u32* p, u32 v){
  __hip_atomic_store(p, v, __ATOMIC_RELAXED, __HIP_MEMORY_SCOPE_AGENT);
}
__device__ __forceinline__ u64 pol64(const u32* p){
  return __hip_atomic_load((const u64*)p, __ATOMIC_RELAXED, __HIP_MEMORY_SCOPE_AGENT);
}
__device__ __forceinline__ u32 pol32(const u32* p){
  return __hip_atomic_load(p, __ATOMIC_RELAXED, __HIP_MEMORY_SCOPE_AGENT);
}

// ---------------- pack / cast kernels ----------------
__global__ void cast_x_kernel(const float* __restrict__ in, u16* __restrict__ out){
  int i = blockIdx.x*256 + threadIdx.x;
  for (; i < 4194304; i += 2048*256){
    f32x4 v = ((const f32x4*)in)[i];
    short4v o;
    o[0]=(short)f2bf(v[0]); o[1]=(short)f2bf(v[1]); o[2]=(short)f2bf(v[2]); o[3]=(short)f2bf(v[3]);
    ((short4v*)out)[i] = o;
  }
}

// w1[4,512,512] -> w1p[n=g*512+h][k]; wx/wh -> wxwhp[lv][n=g*512+h][k(1024): k<512 wx, else wh]
__global__ void pack_w_kernel(const float* __restrict__ w1, const float* __restrict__ wx, const float* __restrict__ wh,
                              u16* __restrict__ w1p, u16* __restrict__ wxwhp){
  int e = blockIdx.x*256 + threadIdx.x;
  for (; e < 7340032; e += 2048*256){
    if (e < 1048576){
      int h = e & 511, k = (e>>9)&511, g = e>>18;
      w1p[(size_t)(g*512+h)*512 + k] = f2bf(w1[(size_t)g*262144 + (size_t)k*512 + h]);
    } else {
      int r = e - 1048576;
      int lv = r >> 21;
      int q = r & 2097151;
      int n = q >> 10, k = q & 1023;
      int g = n >> 9, h = n & 511;
      float v;
      if (k < 512) v = wx[(size_t)lv*1048576 + (size_t)g*262144 + (size_t)k*512 + h];
      else         v = wh[(size_t)lv*1048576 + (size_t)g*262144 + (size_t)(k-512)*512 + h];
      wxwhp[(size_t)lv*2097152 + (size_t)n*1024 + k] = f2bf(v);
    }
  }
}

__global__ void cast_u_kernel(const float* __restrict__ u1, const float* __restrict__ uv,
                              u16* __restrict__ u1p, u16* __restrict__ uv0p){
  int e = blockIdx.x*256 + threadIdx.x;
  for (; e < 1835008; e += 1024*256){
    if (e < 1048576) u1p[e] = f2bf(u1[e]);
    else { int r = e - 1048576; uv0p[r] = f2bf(uv[(size_t)(r>>18)*1048576 + (r & 262143)]); }
  }
}

// ---------------- GEMM: pre1[bt,n] = xb @ w1p^T + b1 (proven) ----------------
__global__ __launch_bounds__(256) void gemm_pre_kernel(
    const u16* __restrict__ A1, const u16* __restrict__ B1,
    const u16* __restrict__ A2, const u16* __restrict__ B2,
    const float* __restrict__ bias, int bmask,
    u16* __restrict__ Out, int nPass)
{
  __shared__ u16 As[128*64];
  __shared__ u16 Bs[128*64];
  const int tid = threadIdx.x;
  const int w = tid>>6, lane = tid&63;
  const int l15 = lane&15, l4 = lane>>4;
  const int m0 = blockIdx.x*128, n0 = blockIdx.y*128;
  const int wm = w>>1, wn = w&1;
  f32x4 acc[4][4];
#pragma unroll
  for (int a=0;a<4;a++)
#pragma unroll
    for (int bq=0;bq<4;bq++) acc[a][bq] = (f32x4){0.f,0.f,0.f,0.f};

  for (int p=0;p<nPass;p++){
    const u16* Ap = p ? A2 : A1;
    const u16* Bp = p ? B2 : B1;
    for (int kt=0;kt<8;kt++){
      const int k0 = kt*64;
      __syncthreads();
#pragma unroll
      for (int i=0;i<4;i++){
        int chunk = w*4 + i;
        int fb = chunk*1024 + lane*16;
        int row = fb>>7;
        int slot = (fb>>4)&7;
        const u16* srcA = Ap + (size_t)(m0+row)*512 + k0 + ((slot ^ (row&7))<<3);
        gld16(srcA, (u16*)As + chunk*512);
        const u16* srcB = Bp + (size_t)(n0+row)*512 + k0 + ((slot ^ (row&7))<<3);
        gld16(srcB, (u16*)Bs + chunk*512);
      }
      __syncthreads();
#pragma unroll
      for (int kk=0;kk<2;kk++){
        short8 af[4], bfq[4];
#pragma unroll
        for (int mi=0;mi<4;mi++){
          int row = wm*64 + mi*16 + l15;
          int s16 = l4 + kk*4;
          af[mi] = *(const short8*)&As[row*64 + ((s16 ^ (row&7))<<3)];
        }
#pragma unroll
        for (int ni=0;ni<4;ni++){
          int row = wn*64 + ni*16 + l15;
          int s16 = l4 + kk*4;
          bfq[ni] = *(const short8*)&Bs[row*64 + ((s16 ^ (row&7))<<3)];
        }
#pragma unroll
        for (int mi=0;mi<4;mi++)
#pragma unroll
          for (int ni=0;ni<4;ni++)
            acc[mi][ni] = __builtin_amdgcn_mfma_f32_16x16x32_bf16(af[mi], bfq[ni], acc[mi][ni], 0,0,0);
      }
    }
  }
#pragma unroll
  for (int ni=0;ni<4;ni++){
    int col = n0 + wn*64 + ni*16 + l15;
    float bb = bias[col & bmask];
#pragma unroll
    for (int mi=0;mi<4;mi++){
#pragma unroll
      for (int i=0;i<4;i++){
        int row = m0 + wm*64 + mi*16 + l4*4 + i;
        Out[(size_t)row*2048 + col] = f2bf(acc[mi][ni][i] + bb);
      }
    }
  }
}

// ================ fused pipelined megakernel ================
// blocks 0..15   : scan layer 0 (16 WG = 8 col x 2 batch)
// blocks 16..27  : scan layers 1..3 (4 WG each)
// blocks 28..123 : pre clusters layers 1..3 (32 WG each: 2 b-half x 16 col-grp)
// hring[l][64][32][512] u32 tagged h; pring[lv][64][32][2048] u32 tagged pre;
// prog[(l-1)*4+sub]: scan layer l progress (backpressure)
__global__ __launch_bounds__(512,2) void mega_kernel(
    const u16* __restrict__ pre1, const u16* __restrict__ u1p,
    const u16* __restrict__ uv0p, const u16* __restrict__ xb,
    const u16* __restrict__ wxwhp, const float* __restrict__ bv,
    u32* hring, u32* pring, u32* prog, float* __restrict__ out)
{
  __shared__ char smem[33024];
  const int bid = blockIdx.x;
  const int tid = threadIdx.x;
  const int lane = tid&63, w = tid>>6;
  const int l15 = lane&15, l4 = lane>>4;

  if (bid < 16){
    // ======== scan layer 0 ========
    u16* hs = (u16*)smem;
    float* recb = (float*)(smem+16384);
    const int gk = bid & 7, gb = bid >> 3;
    const int b0 = gb*16, kb = gk*64;
    const int g = w>>1, ch = w&1;
    short8 bfr[2][16];
#pragma unroll
    for (int n=0;n<2;n++){
      const u16* up = u1p + (size_t)g*262144 + (kb + ch*32 + n*16 + l15);
#pragma unroll
      for (int s=0;s<16;s++){
        int kbase = s*32 + l4*8;
#pragma unroll
        for (int j=0;j<8;j++) bfr[n][s][j] = (short)up[(size_t)(kbase+j)*512];
      }
    }
    { short8 z = {0,0,0,0,0,0,0,0};
      for (int i=tid;i<1024;i+=512) ((short8*)hs)[i]=z; }
    const int b = tid>>5, q = tid&31;
    const int hc2 = q*2;
    float cA=0.f, cB=0.f;
    __syncthreads();

    for (int t=0;t<1024;++t){
      if ((t&15)==0 && t>=32){
        int thr = t-32;
        for(;;){
          int m0=(int)pol32(&prog[0]); m0=imin(m0,(int)pol32(&prog[1]));
          m0=imin(m0,(int)pol32(&prog[2])); m0=imin(m0,(int)pol32(&prog[3]));
          if (m0>=thr) break;
          __builtin_amdgcn_s_sleep(8);
        }
      }
      const u16* prow = pre1 + ((size_t)((b0+b)*1024+t))*2048 + kb + hc2;
      u32 pw0 = *(const u32*)(prow);
      u32 pw1 = *(const u32*)(prow+512);
      u32 pw2 = *(const u32*)(prow+1024);
      u32 pw3 = *(const u32*)(prow+1536);
      f32x4 acc0 = {0.f,0.f,0.f,0.f}, acc1 = {0.f,0.f,0.f,0.f};
      {
        int rb = l15*512, sw = (l15&7)<<3;
#pragma unroll
        for (int s=0;s<16;s++){
          short8 a = *(const short8*)&hs[rb + ((s*32 + l4*8) ^ sw)];
          acc0 = __builtin_amdgcn_mfma_f32_16x16x32_bf16(a, bfr[0][s], acc0, 0,0,0);
          acc1 = __builtin_amdgcn_mfma_f32_16x16x32_bf16(a, bfr[1][s], acc1, 0,0,0);
        }
      }
      {
        int base = g*64 + ch*32 + l15;
#pragma unroll
        for (int i=0;i<4;i++){
          recb[(l4*4+i)*256 + base]      = acc0[i];
          recb[(l4*4+i)*256 + base + 16] = acc1[i];
        }
      }
      __syncthreads();
      float ri0 = recb[b*256 + hc2],       ri1 = recb[b*256 + hc2+1];
      float rf0 = recb[b*256 + 64 + hc2],  rf1 = recb[b*256 + 64 + hc2+1];
      float rg0 = recb[b*256 + 128 + hc2], rg1 = recb[b*256 + 128 + hc2+1];
      float ro0 = recb[b*256 + 192 + hc2], ro1 = recb[b*256 + 192 + hc2+1];
      float gi0 = sigm(bf2f((u16)(pw0&0xffffu)) + ri0), gi1 = sigm(bf2f((u16)(pw0>>16)) + ri1);
      float gf0 = sigm(bf2f((u16)(pw1&0xffffu)) + rf0), gf1 = sigm(bf2f((u16)(pw1>>16)) + rf1);
      float gg0 = sigm(bf2f((u16)(pw2&0xffffu)) + rg0), gg1 = sigm(bf2f((u16)(pw2>>16)) + rg1);
      float go0 = sigm(bf2f((u16)(pw3&0xffffu)) + ro0), go1 = sigm(bf2f((u16)(pw3>>16)) + ro1);
      cA = gf0 + cA + gi0*gg0; float h0v = go0 + tanh_a(cA);
      cB = gf1 + cB + gi1*gg1; float h1v = go1 + tanh_a(cB);
      u16 hb0 = f2bf(h0v), hb1 = f2bf(h1v);
      const u32 tag = (u32)(t+1);
      u32* slot = hring + (size_t)(t&63)*16384;
      u64 msg = (((u64)((tag<<16)|(u32)hb1))<<32) | (u64)((tag<<16)|(u32)hb0);
      pub64(&slot[(size_t)(b0+b)*512 + kb + hc2], msg);
      u32 hpair = (u32)hb0 | ((u32)hb1<<16);
      *(u32*)&hs[b*512 + ((kb+hc2) ^ ((b&7)<<3))] = hpair;
      // gather 448 foreign cols: 7 u64/thread, batched rounds, sleep on retry
      {
        const u32* srcg = slot + (size_t)(b0+b)*512;
        u64 nv[7];
        for(;;){
#pragma unroll
          for (int j=0;j<7;j++){
            int fc = q*14 + 2*j;
            int ac = fc + (fc>=kb ? 64 : 0);
            nv[j] = pol64(&srcg[ac]);
          }
          u32 ok = 1;
#pragma unroll
          for (int j=0;j<7;j++){
            if ((u32)(((u32)nv[j])>>16) != tag) ok=0;
            if ((u32)(nv[j]>>48) != tag) ok=0;
          }
          if (ok) break;
          __builtin_amdgcn_s_sleep(1);
        }
#pragma unroll
        for (int j=0;j<7;j++){
          int fc = q*14 + 2*j;
          int ac = fc + (fc>=kb ? 64 : 0);
          u32 pair = ((u32)nv[j]&0xffffu) | ((u32)((nv[j]>>32)&0xffffu)<<16);
          *(u32*)&hs[b*512 + (ac ^ ((b&7)<<3))] = pair;
        }
      }
      __syncthreads();
    }
  } else if (bid < 28){
    // ======== scan layers 1..3 ========
    u16* hs = (u16*)smem;
    float* recb = (float*)(smem+16384);
    const int l = 1 + ((bid-16)>>2);
    const int lv = l-1;
    const int sub = (bid-16)&3;
    const int ch = sub&1, gb = sub>>1;
    const int b0 = gb*16, cbase = ch*256;
    short8 bfr[2][16];
#pragma unroll
    for (int n=0;n<2;n++){
      const u16* up = uv0p + (size_t)lv*262144 + (cbase + w*32 + n*16 + l15);
#pragma unroll
      for (int s=0;s<16;s++){
        int kbase = s*32 + l4*8;
#pragma unroll
        for (int j=0;j<8;j++) bfr[n][s][j] = (short)up[(size_t)(kbase+j)*512];
      }
    }
    { short8 z = {0,0,0,0,0,0,0,0};
      for (int i=tid;i<1024;i+=512) ((short8*)hs)[i]=z; }
    const int b = tid>>5, q = tid&31;
    const int oc = cbase + q*8;
    float cv[8];
#pragma unroll
    for (int j=0;j<8;j++) cv[j]=0.f;
    u32* hr = hring + (size_t)l*1048576;
    u32* pr = pring + (size_t)lv*4194304;
    const int is_last = (l==3);
    __syncthreads();

    for (int t=0;t<1024;++t){
      const u32 tag = (u32)(t+1);
      if (l<3 && (t&15)==0 && t>=32){
        int thr=t-32;
        const int pbase = l*4;
        for(;;){
          int m0=(int)pol32(&prog[pbase]); m0=imin(m0,(int)pol32(&prog[pbase+1]));
          m0=imin(m0,(int)pol32(&prog[pbase+2])); m0=imin(m0,(int)pol32(&prog[pbase+3]));
          if (m0>=thr) break;
          __builtin_amdgcn_s_sleep(8);
        }
      }
      // issue pre poll (first round) so latency hides under the MFMA
      const u32* ps = pr + (size_t)(t&63)*65536 + (size_t)(b0+b)*2048;
      u64 pv[16];
#pragma unroll
      for (int gq=0;gq<4;gq++)
#pragma unroll
        for (int j=0;j<4;j++)
          pv[gq*4+j] = pol64(&ps[gq*512 + oc + 2*j]);
      // recurrent MFMA (needs only hs from t-1)
      f32x4 acc0={0.f,0.f,0.f,0.f}, acc1={0.f,0.f,0.f,0.f};
      {
        int rb=l15*512, sw=(l15&7)<<3;
#pragma unroll
        for (int s=0;s<16;s++){
          short8 a = *(const short8*)&hs[rb + ((s*32+l4*8)^sw)];
          acc0 = __builtin_amdgcn_mfma_f32_16x16x32_bf16(a, bfr[0][s], acc0, 0,0,0);
          acc1 = __builtin_amdgcn_mfma_f32_16x16x32_bf16(a, bfr[1][s], acc1, 0,0,0);
        }
      }
      {
        int base = w*32 + l15;
#pragma unroll
        for (int i=0;i<4;i++){
          recb[(l4*4+i)*256 + base]    = acc0[i];
          recb[(l4*4+i)*256 + base+16] = acc1[i];
        }
      }
      // verify pre poll, retry with sleep
      for(;;){
        u32 ok=1;
#pragma unroll
        for (int i=0;i<16;i++){
          if ((u32)(((u32)pv[i])>>16) != tag) ok=0;
          if ((u32)(pv[i]>>48) != tag) ok=0;
        }
        if (ok) break;
        __builtin_amdgcn_s_sleep(2);
#pragma unroll
        for (int gq=0;gq<4;gq++)
#pragma unroll
          for (int j=0;j<4;j++)
            pv[gq*4+j] = pol64(&ps[gq*512 + oc + 2*j]);
      }
      __syncthreads();
      short8 hvv; float hf[8]; u32 msgw[8];
#pragma unroll
      for (int j=0;j<8;j++){
        float r = recb[b*256 + q*8 + j];
        int wi = j>>1;
        u32 w0 = (j&1) ? (u32)(pv[wi]>>32)    : (u32)pv[wi];
        u32 w1v= (j&1) ? (u32)(pv[4+wi]>>32)  : (u32)pv[4+wi];
        u32 w2 = (j&1) ? (u32)(pv[8+wi]>>32)  : (u32)pv[8+wi];
        u32 w3 = (j&1) ? (u32)(pv[12+wi]>>32) : (u32)pv[12+wi];
        float gi = sigm(bf2f((u16)(w0&0xffffu)) + r);
        float gf = sigm(bf2f((u16)(w1v&0xffffu)) + r);
        float gg = sigm(bf2f((u16)(w2&0xffffu)) + r);
        float go = sigm(bf2f((u16)(w3&0xffffu)) + r);
        cv[j] = gf + cv[j] + gi*gg;
        float h = go + tanh_a(cv[j]);
        u16 hb = f2bf(h);
        hvv[j]=(short)hb; hf[j]=h; msgw[j] = (tag<<16)|(u32)hb;
      }
      u32* hslot = hr + (size_t)(t&63)*16384 + (size_t)(b0+b)*512;
#pragma unroll
      for (int j=0;j<4;j++){
        u64 m = (((u64)msgw[2*j+1])<<32) | (u64)msgw[2*j];
        pub64(&hslot[oc + 2*j], m);
      }
      *(short8*)&hs[b*512 + (oc ^ ((b&7)<<3))] = hvv;
      if (is_last){
        f32x4 h4a={hf[0],hf[1],hf[2],hf[3]}, h4b={hf[4],hf[5],hf[6],hf[7]};
        *(f32x4*)&out[32768 + ((size_t)((b0+b)*1024+t))*512 + oc]   = h4a;
        *(f32x4*)&out[32768 + ((size_t)((b0+b)*1024+t))*512 + oc+4] = h4b;
        if (t==1023){
          *(f32x4*)&out[(size_t)(b0+b)*512 + oc]   = h4a;
          *(f32x4*)&out[(size_t)(b0+b)*512 + oc+4] = h4b;
          f32x4 c4a={cv[0],cv[1],cv[2],cv[3]}, c4b={cv[4],cv[5],cv[6],cv[7]};
          *(f32x4*)&out[16384 + (size_t)(b0+b)*512 + oc]   = c4a;
          *(f32x4*)&out[16384 + (size_t)(b0+b)*512 + oc+4] = c4b;
        }
      }
      // partner gather (other 256-col half)
      {
        const u32* src = hslot + (ch^1)*256 + q*8;
        u64 nv[4];
        for(;;){
#pragma unroll
          for (int j=0;j<4;j++) nv[j] = pol64(&src[2*j]);
          u32 ok=1;
#pragma unroll
          for (int j=0;j<4;j++){
            if ((u32)(((u32)nv[j])>>16)!=tag) ok=0;
            if ((u32)(nv[j]>>48)!=tag) ok=0;
          }
          if (ok) break;
          __builtin_amdgcn_s_sleep(1);
        }
        short8 hh;
#pragma unroll
        for (int j=0;j<4;j++){
          hh[2*j]   = (short)(u16)(nv[j] & 0xffffu);
          hh[2*j+1] = (short)(u16)((nv[j]>>32) & 0xffffu);
        }
        int pc = (ch^1)*256 + q*8;
        *(short8*)&hs[b*512 + (pc ^ ((b&7)<<3))] = hh;
      }
      __syncthreads();
      if (tid==0) pub32(&prog[(l-1)*4 + sub], (u32)(t+1));
    }
  } else {
    // ======== pre clusters: rec-pre[t] = [x[t] : h_prev[t]] @ [wx;wh]^T + b0 ========
    // 32 WG/layer: (b-half, 128-col group). hstage [16][520] (pad kills bank conflicts).
    u16* hstage = (u16*)smem;
    const int idx = bid - 28;
    const int lv = idx >> 5;
    const int r  = idx & 31;
    const int gb = r & 1, cg = r >> 1;
    const int b0 = gb*16;
    const int c  = cg*128 + w*16 + l15;           // wave = one 16-col tile
    const u16* Bw = wxwhp + (size_t)lv*2097152 + (size_t)c*1024;
    short8 bfr[32];
#pragma unroll
    for (int s=0;s<32;s++) bfr[s] = *(const short8*)&Bw[s*32 + l4*8];
    const float bias = bv[lv*2048 + (c & 511)];
    const int prow_ = tid >> 5;                   // 0..15 local row
    const int px = tid & 31;
    const u32* hrb = hring + (size_t)lv*1048576;
    u32* prb = pring + (size_t)lv*4194304;

    for (int t=0;t<1024;++t){
      const u32 tag = (u32)(t+1);
      // 1) issue h poll (first round): 8 u64, interleaved cols (stride-64)
      const u32* hsrc = hrb + (size_t)(t&63)*16384 + (size_t)(b0+prow_)*512;
      u64 nv[8];
#pragma unroll
      for (int j=0;j<8;j++) nv[j] = pol64(&hsrc[px*2 + 64*j]);
      // 2) x-part MFMA overlaps the poll latency
      f32x4 acc = {0.f,0.f,0.f,0.f};
      const u16* xrow = xb + ((size_t)(b0+l15)*1024 + t)*512;
#pragma unroll
      for (int s=0;s<16;s++){
        short8 a = *(const short8*)&xrow[s*32 + l4*8];
        acc = __builtin_amdgcn_mfma_f32_16x16x32_bf16(a, bfr[s], acc, 0,0,0);
      }
      // 3) verify poll, retry with sleep
      for(;;){
        u32 ok=1;
#pragma unroll
        for (int j=0;j<8;j++){
          if ((u32)(((u32)nv[j])>>16)!=tag) ok=0;
          if ((u32)(nv[j]>>48)!=tag) ok=0;
        }
        if (ok) break;
        __builtin_amdgcn_s_sleep(2);
#pragma unroll
        for (int j=0;j<8;j++) nv[j] = pol64(&hsrc[px*2 + 64*j]);
      }
      // 4) stage h to LDS (bank-clean: bank = px + 4*prow_)
#pragma unroll
      for (int j=0;j<8;j++){
        u32 pair = ((u32)nv[j]&0xffffu) | ((u32)((nv[j]>>32)&0xffffu)<<16);
        *(u32*)&hstage[prow_*520 + px*2 + 64*j] = pair;
      }
      __syncthreads();
      // 5) h-part MFMA
#pragma unroll
      for (int s=0;s<16;s++){
        short8 a = *(const short8*)&hstage[l15*520 + s*32 + l4*8];
        acc = __builtin_amdgcn_mfma_f32_16x16x32_bf16(a, bfr[16+s], acc, 0,0,0);
      }
      // 6) publish tagged pre
      u32* dst = prb + (size_t)(t&63)*65536 + c;
#pragma unroll
      for (int i=0;i<4;i++){
        u32 v = ((u32)f2bf(acc[i]+bias)) | (tag<<16);
        pub32(&dst[(size_t)(b0 + l4*4 + i)*2048], v);
      }
      __syncthreads();
    }
  }
}

extern "C" void kernel_launch(void* const* d_in, const int* in_sizes, int n_in,
                              void* d_out, int out_size, void* d_ws, size_t ws_size,
                              hipStream_t stream)
{
  const float* x  = (const float*)d_in[0];
  const float* w1 = (const float*)d_in[1];
  const float* u1 = (const float*)d_in[2];
  const float* b1 = (const float*)d_in[3];
  const float* wx = (const float*)d_in[4];
  const float* wh = (const float*)d_in[5];
  const float* uv = (const float*)d_in[6];
  const float* bv = (const float*)d_in[7];
  float* out = (float*)d_out;

  char* p = (char*)d_ws;
  u16* pre1  = (u16*)p; p += (size_t)134217728;  // [32768][2048] bf16
  u16* xb    = (u16*)p; p += 33554432;           // [32768][512] bf16
  u16* w1p   = (u16*)p; p += 2097152;
  u16* wxwhp = (u16*)p; p += 12582912;           // 3 x [2048][1024] bf16
  u16* u1p   = (u16*)p; p += 2097152;
  u16* uv0p  = (u16*)p; p += 1572864;
  u32* hring = (u32*)p; p += 16777216;           // 4 x [64][32][512] u32
  u32* pring = (u32*)p; p += 50331648;           // 3 x [64][32][2048] u32
  u32* prog  = (u32*)p; p += 256;
  if ((size_t)(p - (char*)d_ws) > ws_size) return;

  hipMemsetAsync(hring, 0, 16777216, stream);
  hipMemsetAsync(pring, 0, 50331648, stream);
  hipMemsetAsync(prog, 0, 256, stream);
  cast_x_kernel<<<2048,256,0,stream>>>(x, xb);
  pack_w_kernel<<<2048,256,0,stream>>>(w1, wx, wh, w1p, wxwhp);
  cast_u_kernel<<<1024,256,0,stream>>>(u1, uv, u1p, uv0p);

  gemm_pre_kernel<<<dim3(256,16),256,0,stream>>>(xb, w1p, (const u16*)nullptr, (const u16*)nullptr, b1, 2047, pre1, 1);
  mega_kernel<<<124,512,0,stream>>>(pre1, u1p, uv0p, xb, wxwhp, bv, hring, pring, prog, out);
}

// Round 6
// 7624.162 us; speedup vs baseline: 4.0558x; 1.0548x over previous
//
#include <hip/hip_runtime.h>

typedef unsigned short u16;
typedef unsigned int u32;
typedef unsigned long long u64;
typedef __attribute__((ext_vector_type(4))) float f32x4;
typedef __attribute__((ext_vector_type(8))) short short8;
typedef __attribute__((ext_vector_type(4))) short short4v;

__device__ __forceinline__ float bf2f(u16 v){ u32 b = ((u32)v)<<16; float f; __builtin_memcpy(&f,&b,4); return f; }
__device__ __forceinline__ u16 f2bf(float f){ u32 b; __builtin_memcpy(&b,&f,4); b = b + 0x7fffu + ((b>>16)&1u); return (u16)(b>>16); }
__device__ __forceinline__ float sigm(float x){ return 1.f/(1.f+__expf(-x)); }
__device__ __forceinline__ float tanh_a(float x){ return 1.f - 2.f/(__expf(2.f*x)+1.f); }
__device__ __forceinline__ int imin(int a, int b){ return a<b?a:b; }

typedef const __attribute__((address_space(1))) u32* gas1;
typedef __attribute__((address_space(3))) u32* las3;
__device__ __forceinline__ void gld16(const u16* g, u16* l){
  __builtin_amdgcn_global_load_lds((gas1)g, (las3)l, 16, 0, 0);
}

// ---- proven exchange primitives: HIP relaxed agent-scope atomics ----
__device__ __forceinline__ void pub64(u32* p, u64 v){
  __hip_atomic_store((u64*)p, v, __ATOMIC_RELAXED, __HIP_MEMORY_SCOPE_AGENT);
}
__device__ __forceinline__ void pub32(u32* p, u32 v){
  __hip_atomic_store(p, v, __ATOMIC_RELAXED, __HIP_MEMORY_SCOPE_AGENT);
}
__device__ __forceinline__ u64 pol64(const u32* p){
  return __hip_atomic_load((const u64*)p, __ATOMIC_RELAXED, __HIP_MEMORY_SCOPE_AGENT);
}
__device__ __forceinline__ u32 pol32(const u32* p){
  return __hip_atomic_load(p, __ATOMIC_RELAXED, __HIP_MEMORY_SCOPE_AGENT);
}

// ---------------- pack / cast kernels ----------------
// xb layout: [t][b][512] (t-slice contiguous -> L2/L3 friendly streaming)
__global__ void cast_x_kernel(const float* __restrict__ in, u16* __restrict__ out){
  int i = blockIdx.x*256 + threadIdx.x;
  for (; i < 4194304; i += 2048*256){
    f32x4 v = ((const f32x4*)in)[i];
    int e = i*4;
    int b = e >> 19, t = (e >> 9) & 1023, k = e & 511;
    short4v o;
    o[0]=(short)f2bf(v[0]); o[1]=(short)f2bf(v[1]); o[2]=(short)f2bf(v[2]); o[3]=(short)f2bf(v[3]);
    *(short4v*)&out[(size_t)(t*32+b)*512 + k] = o;
  }
}

__global__ void pack_w_kernel(const float* __restrict__ w1, const float* __restrict__ wx, const float* __restrict__ wh,
                              u16* __restrict__ w1p, u16* __restrict__ wxwhp){
  int e = blockIdx.x*256 + threadIdx.x;
  for (; e < 7340032; e += 2048*256){
    if (e < 1048576){
      int h = e & 511, k = (e>>9)&511, g = e>>18;
      w1p[(size_t)(g*512+h)*512 + k] = f2bf(w1[(size_t)g*262144 + (size_t)k*512 + h]);
    } else {
      int r = e - 1048576;
      int lv = r >> 21;
      int q = r & 2097151;
      int n = q >> 10, k = q & 1023;
      int g = n >> 9, h = n & 511;
      float v;
      if (k < 512) v = wx[(size_t)lv*1048576 + (size_t)g*262144 + (size_t)k*512 + h];
      else         v = wh[(size_t)lv*1048576 + (size_t)g*262144 + (size_t)(k-512)*512 + h];
      wxwhp[(size_t)lv*2097152 + (size_t)n*1024 + k] = f2bf(v);
    }
  }
}

__global__ void cast_u_kernel(const float* __restrict__ u1, const float* __restrict__ uv,
                              u16* __restrict__ u1p, u16* __restrict__ uv0p){
  int e = blockIdx.x*256 + threadIdx.x;
  for (; e < 1835008; e += 1024*256){
    if (e < 1048576) u1p[e] = f2bf(u1[e]);
    else { int r = e - 1048576; uv0p[r] = f2bf(uv[(size_t)(r>>18)*1048576 + (r & 262143)]); }
  }
}

// ---------------- GEMM: pre1[tb,n] = xb @ w1p^T + b1 (rows are t*32+b) ----------------
__global__ __launch_bounds__(256) void gemm_pre_kernel(
    const u16* __restrict__ A1, const u16* __restrict__ B1,
    const float* __restrict__ bias, int bmask,
    u16* __restrict__ Out)
{
  __shared__ u16 As[128*64];
  __shared__ u16 Bs[128*64];
  const int tid = threadIdx.x;
  const int w = tid>>6, lane = tid&63;
  const int l15 = lane&15, l4 = lane>>4;
  const int m0 = blockIdx.x*128, n0 = blockIdx.y*128;
  const int wm = w>>1, wn = w&1;
  f32x4 acc[4][4];
#pragma unroll
  for (int a=0;a<4;a++)
#pragma unroll
    for (int bq=0;bq<4;bq++) acc[a][bq] = (f32x4){0.f,0.f,0.f,0.f};

  for (int kt=0;kt<8;kt++){
    const int k0 = kt*64;
    __syncthreads();
#pragma unroll
    for (int i=0;i<4;i++){
      int chunk = w*4 + i;
      int fb = chunk*1024 + lane*16;
      int row = fb>>7;
      int slot = (fb>>4)&7;
      const u16* srcA = A1 + (size_t)(m0+row)*512 + k0 + ((slot ^ (row&7))<<3);
      gld16(srcA, (u16*)As + chunk*512);
      const u16* srcB = B1 + (size_t)(n0+row)*512 + k0 + ((slot ^ (row&7))<<3);
      gld16(srcB, (u16*)Bs + chunk*512);
    }
    __syncthreads();
#pragma unroll
    for (int kk=0;kk<2;kk++){
      short8 af[4], bfq[4];
#pragma unroll
      for (int mi=0;mi<4;mi++){
        int row = wm*64 + mi*16 + l15;
        int s16 = l4 + kk*4;
        af[mi] = *(const short8*)&As[row*64 + ((s16 ^ (row&7))<<3)];
      }
#pragma unroll
      for (int ni=0;ni<4;ni++){
        int row = wn*64 + ni*16 + l15;
        int s16 = l4 + kk*4;
        bfq[ni] = *(const short8*)&Bs[row*64 + ((s16 ^ (row&7))<<3)];
      }
#pragma unroll
      for (int mi=0;mi<4;mi++)
#pragma unroll
        for (int ni=0;ni<4;ni++)
          acc[mi][ni] = __builtin_amdgcn_mfma_f32_16x16x32_bf16(af[mi], bfq[ni], acc[mi][ni], 0,0,0);
    }
  }
#pragma unroll
  for (int ni=0;ni<4;ni++){
    int col = n0 + wn*64 + ni*16 + l15;
    float bb = bias[col & bmask];
#pragma unroll
    for (int mi=0;mi<4;mi++){
#pragma unroll
      for (int i=0;i<4;i++){
        int row = m0 + wm*64 + mi*16 + l4*4 + i;
        Out[(size_t)row*2048 + col] = f2bf(acc[mi][ni][i] + bb);
      }
    }
  }
}

// ================ fused pipelined megakernel ================
// blocks 0..15   : scan layer 0 ; 16..27: scan layers 1..3 ; 28..123: pre clusters
// prog[0..11]: scan1-3 step flags; prog[32..47]: scan0 step flags;
// prog[64..159]: pre flags [lv*32 + r]. Flags gate RETRY paths only (tags stay truth).
__global__ __launch_bounds__(512,2) void mega_kernel(
    const u16* __restrict__ pre1, const u16* __restrict__ u1p,
    const u16* __restrict__ uv0p, const u16* __restrict__ xb,
    const u16* __restrict__ wxwhp, const float* __restrict__ bv,
    u32* hring, u32* pring, u32* prog, float* __restrict__ out)
{
  __shared__ char smem[33024];
  const int bid = blockIdx.x;
  const int tid = threadIdx.x;
  const int lane = tid&63, w = tid>>6;
  const int l15 = lane&15, l4 = lane>>4;

  if (bid < 16){
    // ======== scan layer 0 ========
    u16* hs = (u16*)smem;
    float* recb = (float*)(smem+16384);
    const int gk = bid & 7, gb = bid >> 3;
    const int b0 = gb*16, kb = gk*64;
    const int g = w>>1, ch = w&1;
    short8 bfr[2][16];
#pragma unroll
    for (int n=0;n<2;n++){
      const u16* up = u1p + (size_t)g*262144 + (kb + ch*32 + n*16 + l15);
#pragma unroll
      for (int s=0;s<16;s++){
        int kbase = s*32 + l4*8;
#pragma unroll
        for (int j=0;j<8;j++) bfr[n][s][j] = (short)up[(size_t)(kbase+j)*512];
      }
    }
    { short8 z = {0,0,0,0,0,0,0,0};
      for (int i=tid;i<1024;i+=512) ((short8*)hs)[i]=z; }
    const int b = tid>>5, q = tid&31;
    const int hc2 = q*2;
    float cA=0.f, cB=0.f;
    __syncthreads();

    for (int t=0;t<1024;++t){
      if ((t&15)==0 && t>=32){
        int thr = t-32;
        for(;;){
          int m0=(int)pol32(&prog[0]); m0=imin(m0,(int)pol32(&prog[1]));
          m0=imin(m0,(int)pol32(&prog[2])); m0=imin(m0,(int)pol32(&prog[3]));
          if (m0>=thr) break;
          __builtin_amdgcn_s_sleep(8);
        }
      }
      const u16* prow = pre1 + ((size_t)(t*32 + b0 + b))*2048 + kb + hc2;
      u32 pw0 = *(const u32*)(prow);
      u32 pw1 = *(const u32*)(prow+512);
      u32 pw2 = *(const u32*)(prow+1024);
      u32 pw3 = *(const u32*)(prow+1536);
      f32x4 acc0 = {0.f,0.f,0.f,0.f}, acc1 = {0.f,0.f,0.f,0.f};
      {
        int rb = l15*512, sw = (l15&7)<<3;
#pragma unroll
        for (int s=0;s<16;s++){
          short8 a = *(const short8*)&hs[rb + ((s*32 + l4*8) ^ sw)];
          acc0 = __builtin_amdgcn_mfma_f32_16x16x32_bf16(a, bfr[0][s], acc0, 0,0,0);
          acc1 = __builtin_amdgcn_mfma_f32_16x16x32_bf16(a, bfr[1][s], acc1, 0,0,0);
        }
      }
      {
        int base = g*64 + ch*32 + l15;
#pragma unroll
        for (int i=0;i<4;i++){
          recb[(l4*4+i)*256 + base]      = acc0[i];
          recb[(l4*4+i)*256 + base + 16] = acc1[i];
        }
      }
      __syncthreads();
      float ri0 = recb[b*256 + hc2],       ri1 = recb[b*256 + hc2+1];
      float rf0 = recb[b*256 + 64 + hc2],  rf1 = recb[b*256 + 64 + hc2+1];
      float rg0 = recb[b*256 + 128 + hc2], rg1 = recb[b*256 + 128 + hc2+1];
      float ro0 = recb[b*256 + 192 + hc2], ro1 = recb[b*256 + 192 + hc2+1];
      float gi0 = sigm(bf2f((u16)(pw0&0xffffu)) + ri0), gi1 = sigm(bf2f((u16)(pw0>>16)) + ri1);
      float gf0 = sigm(bf2f((u16)(pw1&0xffffu)) + rf0), gf1 = sigm(bf2f((u16)(pw1>>16)) + rf1);
      float gg0 = sigm(bf2f((u16)(pw2&0xffffu)) + rg0), gg1 = sigm(bf2f((u16)(pw2>>16)) + rg1);
      float go0 = sigm(bf2f((u16)(pw3&0xffffu)) + ro0), go1 = sigm(bf2f((u16)(pw3>>16)) + ro1);
      cA = gf0 + cA + gi0*gg0; float h0v = go0 + tanh_a(cA);
      cB = gf1 + cB + gi1*gg1; float h1v = go1 + tanh_a(cB);
      u16 hb0 = f2bf(h0v), hb1 = f2bf(h1v);
      const u32 tag = (u32)(t+1);
      u32* slot = hring + (size_t)(t&63)*16384;
      u64 msg = (((u64)((tag<<16)|(u32)hb1))<<32) | (u64)((tag<<16)|(u32)hb0);
      pub64(&slot[(size_t)(b0+b)*512 + kb + hc2], msg);
      u32 hpair = (u32)hb0 | ((u32)hb1<<16);
      *(u32*)&hs[b*512 + ((kb+hc2) ^ ((b&7)<<3))] = hpair;
      // gather 448 foreign cols (cyclic edge: pure tag-poll, no flag)
      {
        const u32* srcg = slot + (size_t)(b0+b)*512;
        u64 nv[7];
        for(;;){
#pragma unroll
          for (int j=0;j<7;j++){
            int fc = q*14 + 2*j;
            int ac = fc + (fc>=kb ? 64 : 0);
            nv[j] = pol64(&srcg[ac]);
          }
          u32 ok = 1;
#pragma unroll
          for (int j=0;j<7;j++){
            if ((u32)(((u32)nv[j])>>16) != tag) ok=0;
            if ((u32)(nv[j]>>48) != tag) ok=0;
          }
          if (ok) break;
          __builtin_amdgcn_s_sleep(1);
        }
#pragma unroll
        for (int j=0;j<7;j++){
          int fc = q*14 + 2*j;
          int ac = fc + (fc>=kb ? 64 : 0);
          u32 pair = ((u32)nv[j]&0xffffu) | ((u32)((nv[j]>>32)&0xffffu)<<16);
          *(u32*)&hs[b*512 + (ac ^ ((b&7)<<3))] = pair;
        }
      }
      __syncthreads();
      if (tid==0) pub32(&prog[32+bid], (u32)(t+1));
    }
  } else if (bid < 28){
    // ======== scan layers 1..3 ========
    u16* hs = (u16*)smem;
    float* recb = (float*)(smem+16384);
    const int l = 1 + ((bid-16)>>2);
    const int lv = l-1;
    const int sub = (bid-16)&3;
    const int ch = sub&1, gb = sub>>1;
    const int b0 = gb*16, cbase = ch*256;
    short8 bfr[2][16];
#pragma unroll
    for (int n=0;n<2;n++){
      const u16* up = uv0p + (size_t)lv*262144 + (cbase + w*32 + n*16 + l15);
#pragma unroll
      for (int s=0;s<16;s++){
        int kbase = s*32 + l4*8;
#pragma unroll
        for (int j=0;j<8;j++) bfr[n][s][j] = (short)up[(size_t)(kbase+j)*512];
      }
    }
    { short8 z = {0,0,0,0,0,0,0,0};
      for (int i=tid;i<1024;i+=512) ((short8*)hs)[i]=z; }
    const int b = tid>>5, q = tid&31;
    const int oc = cbase + q*8;
    float cv[8];
#pragma unroll
    for (int j=0;j<8;j++) cv[j]=0.f;
    u32* hr = hring + (size_t)l*1048576;
    u32* pr = pring + (size_t)lv*4194304;
    const int is_last = (l==3);
    __syncthreads();

    for (int t=0;t<1024;++t){
      const u32 tag = (u32)(t+1);
      if (l<3 && (t&15)==0 && t>=32){
        int thr=t-32;
        const int pbase = l*4;
        for(;;){
          int m0=(int)pol32(&prog[pbase]); m0=imin(m0,(int)pol32(&prog[pbase+1]));
          m0=imin(m0,(int)pol32(&prog[pbase+2])); m0=imin(m0,(int)pol32(&prog[pbase+3]));
          if (m0>=thr) break;
          __builtin_amdgcn_s_sleep(8);
        }
      }
      // issue pre poll (first round) so latency hides under the MFMA
      const u32* ps = pr + (size_t)(t&63)*65536 + (size_t)(b0+b)*2048;
      u64 pv[16];
#pragma unroll
      for (int gq=0;gq<4;gq++)
#pragma unroll
        for (int j=0;j<4;j++)
          pv[gq*4+j] = pol64(&ps[gq*512 + oc + 2*j]);
      // recurrent MFMA (needs only hs from t-1)
      f32x4 acc0={0.f,0.f,0.f,0.f}, acc1={0.f,0.f,0.f,0.f};
      {
        int rb=l15*512, sw=(l15&7)<<3;
#pragma unroll
        for (int s=0;s<16;s++){
          short8 a = *(const short8*)&hs[rb + ((s*32+l4*8)^sw)];
          acc0 = __builtin_amdgcn_mfma_f32_16x16x32_bf16(a, bfr[0][s], acc0, 0,0,0);
          acc1 = __builtin_amdgcn_mfma_f32_16x16x32_bf16(a, bfr[1][s], acc1, 0,0,0);
        }
      }
      {
        int base = w*32 + l15;
#pragma unroll
        for (int i=0;i<4;i++){
          recb[(l4*4+i)*256 + base]    = acc0[i];
          recb[(l4*4+i)*256 + base+16] = acc1[i];
        }
      }
      // verify pre poll; on failure gate on pre-cluster flags (forward edge)
      for(;;){
        u32 ok=1;
#pragma unroll
        for (int i=0;i<16;i++){
          if ((u32)(((u32)pv[i])>>16) != tag) ok=0;
          if ((u32)(pv[i]>>48) != tag) ok=0;
        }
        if (ok) break;
        for(;;){
          int mn = 0x7fffffff;
#pragma unroll
          for (int g=0; g<4; g++){
            int cg0 = g*4 + ch*2;
            mn = imin(mn, (int)pol32(&prog[64 + lv*32 + (cg0*2+gb)]));
            mn = imin(mn, (int)pol32(&prog[64 + lv*32 + ((cg0+1)*2+gb)]));
          }
          if (mn >= (int)tag) break;
          __builtin_amdgcn_s_sleep(4);
        }
#pragma unroll
        for (int gq=0;gq<4;gq++)
#pragma unroll
          for (int j=0;j<4;j++)
            pv[gq*4+j] = pol64(&ps[gq*512 + oc + 2*j]);
      }
      __syncthreads();
      short8 hvv; float hf[8]; u32 msgw[8];
#pragma unroll
      for (int j=0;j<8;j++){
        float r = recb[b*256 + q*8 + j];
        int wi = j>>1;
        u32 w0 = (j&1) ? (u32)(pv[wi]>>32)    : (u32)pv[wi];
        u32 w1v= (j&1) ? (u32)(pv[4+wi]>>32)  : (u32)pv[4+wi];
        u32 w2 = (j&1) ? (u32)(pv[8+wi]>>32)  : (u32)pv[8+wi];
        u32 w3 = (j&1) ? (u32)(pv[12+wi]>>32) : (u32)pv[12+wi];
        float gi = sigm(bf2f((u16)(w0&0xffffu)) + r);
        float gf = sigm(bf2f((u16)(w1v&0xffffu)) + r);
        float gg = sigm(bf2f((u16)(w2&0xffffu)) + r);
        float go = sigm(bf2f((u16)(w3&0xffffu)) + r);
        cv[j] = gf + cv[j] + gi*gg;
        float h = go + tanh_a(cv[j]);
        u16 hb = f2bf(h);
        hvv[j]=(short)hb; hf[j]=h; msgw[j] = (tag<<16)|(u32)hb;
      }
      u32* hslot = hr + (size_t)(t&63)*16384 + (size_t)(b0+b)*512;
#pragma unroll
      for (int j=0;j<4;j++){
        u64 m = (((u64)msgw[2*j+1])<<32) | (u64)msgw[2*j];
        pub64(&hslot[oc + 2*j], m);
      }
      *(short8*)&hs[b*512 + (oc ^ ((b&7)<<3))] = hvv;
      if (is_last){
        f32x4 h4a={hf[0],hf[1],hf[2],hf[3]}, h4b={hf[4],hf[5],hf[6],hf[7]};
        *(f32x4*)&out[32768 + ((size_t)((b0+b)*1024+t))*512 + oc]   = h4a;
        *(f32x4*)&out[32768 + ((size_t)((b0+b)*1024+t))*512 + oc+4] = h4b;
        if (t==1023){
          *(f32x4*)&out[(size_t)(b0+b)*512 + oc]   = h4a;
          *(f32x4*)&out[(size_t)(b0+b)*512 + oc+4] = h4b;
          f32x4 c4a={cv[0],cv[1],cv[2],cv[3]}, c4b={cv[4],cv[5],cv[6],cv[7]};
          *(f32x4*)&out[16384 + (size_t)(b0+b)*512 + oc]   = c4a;
          *(f32x4*)&out[16384 + (size_t)(b0+b)*512 + oc+4] = c4b;
        }
      }
      // partner gather (cyclic edge: pure tag-poll)
      {
        const u32* src = hslot + (ch^1)*256 + q*8;
        u64 nv[4];
        for(;;){
#pragma unroll
          for (int j=0;j<4;j++) nv[j] = pol64(&src[2*j]);
          u32 ok=1;
#pragma unroll
          for (int j=0;j<4;j++){
            if ((u32)(((u32)nv[j])>>16)!=tag) ok=0;
            if ((u32)(nv[j]>>48)!=tag) ok=0;
          }
          if (ok) break;
          __builtin_amdgcn_s_sleep(1);
        }
        short8 hh;
#pragma unroll
        for (int j=0;j<4;j++){
          hh[2*j]   = (short)(u16)(nv[j] & 0xffffu);
          hh[2*j+1] = (short)(u16)((nv[j]>>32) & 0xffffu);
        }
        int pc = (ch^1)*256 + q*8;
        *(short8*)&hs[b*512 + (pc ^ ((b&7)<<3))] = hh;
      }
      __syncthreads();
      if (tid==0) pub32(&prog[(l-1)*4 + sub], (u32)(t+1));
    }
  } else {
    // ======== pre clusters: rec-pre[t] = [x[t] : h_prev[t]] @ [wx;wh]^T + b0 ========
    u16* hstage = (u16*)smem;
    const int idx = bid - 28;
    const int lv = idx >> 5;
    const int r  = idx & 31;
    const int gb = r & 1, cg = r >> 1;
    const int b0 = gb*16;
    const int c  = cg*128 + w*16 + l15;
    const u16* Bw = wxwhp + (size_t)lv*2097152 + (size_t)c*1024;
    short8 bfr[32];
#pragma unroll
    for (int s=0;s<32;s++) bfr[s] = *(const short8*)&Bw[s*32 + l4*8];
    const float bias = bv[lv*2048 + (c & 511)];
    const int prow_ = tid >> 5;
    const int px = tid & 31;
    const u32* hrb = hring + (size_t)lv*1048576;
    u32* prb = pring + (size_t)lv*4194304;

    for (int t=0;t<1024;++t){
      const u32 tag = (u32)(t+1);
      // 1) issue h poll (first round)
      const u32* hsrc = hrb + (size_t)(t&63)*16384 + (size_t)(b0+prow_)*512;
      u64 nv[8];
#pragma unroll
      for (int j=0;j<8;j++) nv[j] = pol64(&hsrc[px*2 + 64*j]);
      // 2) x-part MFMA overlaps the poll latency (xb now [t][b][512] -> L3-hot)
      f32x4 acc = {0.f,0.f,0.f,0.f};
      const u16* xrow = xb + (size_t)(t*32 + b0 + l15)*512;
#pragma unroll
      for (int s=0;s<16;s++){
        short8 a = *(const short8*)&xrow[s*32 + l4*8];
        acc = __builtin_amdgcn_mfma_f32_16x16x32_bf16(a, bfr[s], acc, 0,0,0);
      }
      // 3) verify; on failure gate on producer flags (forward edge), then re-read
      for(;;){
        u32 ok=1;
#pragma unroll
        for (int j=0;j<8;j++){
          if ((u32)(((u32)nv[j])>>16)!=tag) ok=0;
          if ((u32)(nv[j]>>48)!=tag) ok=0;
        }
        if (ok) break;
        if (lv==0){
          for(;;){
            int mn = 0x7fffffff;
#pragma unroll
            for (int j=0;j<8;j++) mn = imin(mn, (int)pol32(&prog[32 + gb*8 + j]));
            if (mn >= (int)tag) break;
            __builtin_amdgcn_s_sleep(4);
          }
        } else {
          for(;;){
            int a2 = (int)pol32(&prog[(lv-1)*4 + gb*2]);
            int c2 = (int)pol32(&prog[(lv-1)*4 + gb*2 + 1]);
            if (imin(a2,c2) >= (int)tag) break;
            __builtin_amdgcn_s_sleep(4);
          }
        }
#pragma unroll
        for (int j=0;j<8;j++) nv[j] = pol64(&hsrc[px*2 + 64*j]);
      }
      // 4) stage h to LDS (pad-520 keeps banks clean)
#pragma unroll
      for (int j=0;j<8;j++){
        u32 pair = ((u32)nv[j]&0xffffu) | ((u32)((nv[j]>>32)&0xffffu)<<16);
        *(u32*)&hstage[prow_*520 + px*2 + 64*j] = pair;
      }
      __syncthreads();
      // 5) h-part MFMA
#pragma unroll
      for (int s=0;s<16;s++){
        short8 a = *(const short8*)&hstage[l15*520 + s*32 + l4*8];
        acc = __builtin_amdgcn_mfma_f32_16x16x32_bf16(a, bfr[16+s], acc, 0,0,0);
      }
      // 6) publish tagged pre
      u32* dst = prb + (size_t)(t&63)*65536 + c;
#pragma unroll
      for (int i=0;i<4;i++){
        u32 v = ((u32)f2bf(acc[i]+bias)) | (tag<<16);
        pub32(&dst[(size_t)(b0 + l4*4 + i)*2048], v);
      }
      __syncthreads();
      if (tid==0) pub32(&prog[64 + lv*32 + r], (u32)(t+1));
    }
  }
}

extern "C" void kernel_launch(void* const* d_in, const int* in_sizes, int n_in,
                              void* d_out, int out_size, void* d_ws, size_t ws_size,
                              hipStream_t stream)
{
  const float* x  = (const float*)d_in[0];
  const float* w1 = (const float*)d_in[1];
  const float* u1 = (const float*)d_in[2];
  const float* b1 = (const float*)d_in[3];
  const float* wx = (const float*)d_in[4];
  const float* wh = (const float*)d_in[5];
  const float* uv = (const float*)d_in[6];
  const float* bv = (const float*)d_in[7];
  float* out = (float*)d_out;

  char* p = (char*)d_ws;
  u16* pre1  = (u16*)p; p += (size_t)134217728;  // [1024*32][2048] bf16, rows t*32+b
  u16* xb    = (u16*)p; p += 33554432;           // [1024][32][512] bf16
  u16* w1p   = (u16*)p; p += 2097152;
  u16* wxwhp = (u16*)p; p += 12582912;           // 3 x [2048][1024] bf16
  u16* u1p   = (u16*)p; p += 2097152;
  u16* uv0p  = (u16*)p; p += 1572864;
  u32* hring = (u32*)p; p += 16777216;           // 4 x [64][32][512] u32
  u32* pring = (u32*)p; p += 50331648;           // 3 x [64][32][2048] u32
  u32* prog  = (u32*)p; p += 1024;
  if ((size_t)(p - (char*)d_ws) > ws_size) return;

  hipMemsetAsync(hring, 0, 16777216, stream);
  hipMemsetAsync(pring, 0, 50331648, stream);
  hipMemsetAsync(prog, 0, 1024, stream);
  cast_x_kernel<<<2048,256,0,stream>>>(x, xb);
  pack_w_kernel<<<2048,256,0,stream>>>(w1, wx, wh, w1p, wxwhp);
  cast_u_kernel<<<1024,256,0,stream>>>(u1, uv, u1p, uv0p);

  gemm_pre_kernel<<<dim3(256,16),256,0,stream>>>(xb, w1p, b1, 2047, pre1);
  mega_kernel<<<124,512,0,stream>>>(pre1, u1p, uv0p, xb, wxwhp, bv, hring, pring, prog, out);
}